// Round 6
// baseline (3694.587 us; speedup 1.0000x reference)
//
#include <hip/hip_runtime.h>
#include <cstdint>
#include <cstddef>

#define DT_F 0.5f
#define PK_WGS 512
#define PK_THREADS 512
#define PK_NCAP 200   // max nodes per workgroup staged in LDS (200*64*4 = 51200 B)

// ---------------------------------------------------------------------------
// edge_index dtype detection (reference says int64; harness doc says int).
__global__ void detect_i64(const long long* __restrict__ ei, int E, int n,
                           int* __restrict__ flag) {
    __shared__ int ok;
    if (threadIdx.x == 0) ok = 1;
    __syncthreads();
    int m = E < 2048 ? E : 2048;
    for (int i = threadIdx.x; i < m; i += blockDim.x) {
        long long v = ei[i];
        if (v < 0 || v >= (long long)n) ok = 0;  // benign race, all write 0
    }
    __syncthreads();
    if (threadIdx.x == 0) flag[0] = ok;
}

__device__ __forceinline__ int ld_idx(const void* ei, size_t pos, int w64) {
    return w64 ? (int)((const long long*)ei)[pos] : ((const int*)ei)[pos];
}

// ---------------------------------------------------------------------------
// CSR build: in-degree histogram -> exclusive scan -> atomic-cursor fill.
__global__ void k_count(const void* __restrict__ ei, const int* __restrict__ flag,
                        int E, int* __restrict__ cnt) {
    int e = blockIdx.x * blockDim.x + threadIdx.x;
    if (e >= E) return;
    int d = ld_idx(ei, (size_t)E + e, flag[0]);
    atomicAdd(&cnt[d], 1);
}

#define SCAN_B 1024
__global__ void k_scan1(const int* __restrict__ cnt, int* __restrict__ part,
                        int* __restrict__ bsum, int n) {
    __shared__ int sh[SCAN_B];
    int t = threadIdx.x;
    int g = blockIdx.x * SCAN_B + t;
    int v = g < n ? cnt[g] : 0;
    sh[t] = v;
    __syncthreads();
    for (int o = 1; o < SCAN_B; o <<= 1) {
        int x = t >= o ? sh[t - o] : 0;
        __syncthreads();
        sh[t] += x;
        __syncthreads();
    }
    if (g < n) part[g] = sh[t] - v;              // exclusive
    if (t == SCAN_B - 1) bsum[blockIdx.x] = sh[t];
}

__global__ void k_scan2(int* __restrict__ bsum, int nb) {  // nb <= 1024
    __shared__ int sh[SCAN_B];
    int t = threadIdx.x;
    int v = t < nb ? bsum[t] : 0;
    sh[t] = v;
    __syncthreads();
    for (int o = 1; o < SCAN_B; o <<= 1) {
        int x = t >= o ? sh[t - o] : 0;
        __syncthreads();
        sh[t] += x;
        __syncthreads();
    }
    if (t < nb) bsum[t] = sh[t] - v;             // exclusive
}

__global__ void k_scan3(const int* __restrict__ part, const int* __restrict__ bsum,
                        int* __restrict__ rowptr, int n, int E) {
    int g = blockIdx.x * SCAN_B + threadIdx.x;
    if (g < n) rowptr[g] = part[g] + bsum[blockIdx.x];
    if (g == 0) rowptr[n] = E;
}

__global__ void k_fill(const void* __restrict__ ei, const float* __restrict__ ew,
                       const int* __restrict__ flag, int E,
                       int* __restrict__ cursor,
                       int* __restrict__ cols, float* __restrict__ vals) {
    int e = blockIdx.x * blockDim.x + threadIdx.x;
    if (e >= E) return;
    int w64 = flag[0];
    int s = ld_idx(ei, e, w64);
    int d = ld_idx(ei, (size_t)E + e, w64);
    int p = atomicAdd(&cursor[d], 1);
    cols[p] = s;
    vals[p] = ew[e];
}

// ---------------------------------------------------------------------------
// Precompute: PM = nf @ W_msg[:64];  HC = nf @ W_self[:64] + b_h.
// 4 nodes per wave -> 8 independent FMA chains (ILP fix: was 30% VALUBusy).
__global__ void proj_kernel(const float* __restrict__ nf,
                            const float* __restrict__ Wm,   // (65,64) row-major
                            const float* __restrict__ Wsf,  // (65,64)
                            const float* __restrict__ bh,
                            float* __restrict__ PM, float* __restrict__ HC,
                            int n) {
    __shared__ float sWm[64 * 64];
    __shared__ float sWs[64 * 64];
    for (int i = threadIdx.x; i < 64 * 64; i += blockDim.x) {
        sWm[i] = Wm[i];
        sWs[i] = Wsf[i];
    }
    __syncthreads();
    int wave = (blockIdx.x * blockDim.x + threadIdx.x) >> 6;
    int lane = threadIdx.x & 63;
    int n0 = wave * 4;
    if (n0 >= n) return;
    float a0 = nf[(size_t)n0 * 64 + lane];
    float a1 = (n0 + 1 < n) ? nf[(size_t)(n0 + 1) * 64 + lane] : 0.f;
    float a2 = (n0 + 2 < n) ? nf[(size_t)(n0 + 2) * 64 + lane] : 0.f;
    float a3 = (n0 + 3 < n) ? nf[(size_t)(n0 + 3) * 64 + lane] : 0.f;
    float am0 = 0.f, am1 = 0.f, am2 = 0.f, am3 = 0.f;
    float as0 = 0.f, as1 = 0.f, as2 = 0.f, as3 = 0.f;
#pragma unroll 16
    for (int k = 0; k < 64; ++k) {
        float wmv = sWm[k * 64 + lane];
        float wsv = sWs[k * 64 + lane];
        float v0 = __shfl(a0, k), v1 = __shfl(a1, k);
        float v2 = __shfl(a2, k), v3 = __shfl(a3, k);
        am0 = fmaf(v0, wmv, am0); as0 = fmaf(v0, wsv, as0);
        am1 = fmaf(v1, wmv, am1); as1 = fmaf(v1, wsv, as1);
        am2 = fmaf(v2, wmv, am2); as2 = fmaf(v2, wsv, as2);
        am3 = fmaf(v3, wmv, am3); as3 = fmaf(v3, wsv, as3);
    }
    float bhl = bh[lane];
    PM[(size_t)n0 * 64 + lane] = am0;
    HC[(size_t)n0 * 64 + lane] = as0 + bhl;
    if (n0 + 1 < n) { PM[(size_t)(n0+1)*64 + lane] = am1; HC[(size_t)(n0+1)*64 + lane] = as1 + bhl; }
    if (n0 + 2 < n) { PM[(size_t)(n0+2)*64 + lane] = am2; HC[(size_t)(n0+2)*64 + lane] = as2 + bhl; }
    if (n0 + 3 < n) { PM[(size_t)(n0+3)*64 + lane] = am3; HC[(size_t)(n0+3)*64 + lane] = as3 + bhl; }
}

// Hoisted constant aggregation, CSR form (no atomics):
// HC[d] += sum_{e in in-edges(d)} ew_e * PM[src_e]
__global__ void edge_wide_csr(const int* __restrict__ rowptr,
                              const int* __restrict__ cols,
                              const float* __restrict__ vals,
                              const float* __restrict__ PM,
                              float* __restrict__ HC, int n) {
    int wave = (blockIdx.x * blockDim.x + threadIdx.x) >> 6;
    int lane = threadIdx.x & 63;
    if (wave >= n) return;
    int r0 = rowptr[wave], r1 = rowptr[wave + 1];
    float acc = 0.f;
    for (int e = r0; e < r1; ++e) {
        int s = cols[e];            // wave-uniform broadcast load
        float w = vals[e];
        acc = fmaf(w, PM[(size_t)s * 64 + lane], acc);  // coalesced 256B row
    }
    size_t o = (size_t)wave * 64 + lane;
    HC[o] += acc;
}

// ---------------------------------------------------------------------------
// Persistent scan kernel: all T steps in ONE dispatch. Each wg stages its
// HC slice (<=200 nodes * 256B = 50KB) + S slice in LDS once; per step:
// force (CSR, registers) -> h -> beta/gamma -> SIR; then a grid-wide
// atomic-counter barrier (device scope, monotonic) before the next step.
// 512 wgs * 512 thr = 2 wg/CU, 16 waves/CU, 100KB LDS/CU -> co-resident.
__launch_bounds__(PK_THREADS, 4)
__global__ void persist_steps(const int* __restrict__ rowptr,
                              const int* __restrict__ cols,
                              const float* __restrict__ vals,
                              const float* __restrict__ HC,
                              const float* __restrict__ wmL,
                              const float* __restrict__ wsL,
                              const float* __restrict__ wb, const float* __restrict__ bb,
                              const float* __restrict__ wg_, const float* __restrict__ bg,
                              const float* __restrict__ S0,
                              const float* __restrict__ I0,
                              float* __restrict__ Ib0, float* __restrict__ Ib1,
                              float* __restrict__ out,
                              float* __restrict__ beta_out, float* __restrict__ gamma_out,
                              int n, int T, int nper, int* __restrict__ ctr) {
    __shared__ float sHC[PK_NCAP * 64];
    __shared__ float sS[PK_NCAP];
    int tid  = threadIdx.x;
    int lane = tid & 63;
    int wave = tid >> 6;                       // 0..7
    int base = blockIdx.x * nper;
    int nloc = n - base;
    if (nloc > nper) nloc = nper;
    if (nloc < 0) nloc = 0;
    for (int i = tid; i < nloc * 64; i += PK_THREADS)
        sHC[i] = HC[(size_t)base * 64 + i];
    for (int i = tid; i < nloc; i += PK_THREADS)
        sS[i] = S0[base + i];
    float wmLl = wmL[lane], wsLl = wsL[lane];
    float wbl = wb[lane], wgl = wg_[lane];
    float bbs = bb[0], bgs = bg[0];
    __syncthreads();

    for (int t = 0; t < T; ++t) {
        const float* Iold = (t == 0) ? I0 : ((t & 1) ? Ib0 : Ib1);
        float*       Inew = (t & 1) ? Ib1 : Ib0;
        float*       Iseq = out + (size_t)t * n;
        int last = (t == T - 1);
        for (int ni = wave; ni < nloc; ni += PK_THREADS / 64) {
            int node = base + ni;
            int r0 = rowptr[node], r1 = rowptr[node + 1];
            float f = 0.f;
            for (int e = r0 + lane; e < r1; e += 64)
                f = fmaf(vals[e], Iold[cols[e]], f);
#pragma unroll
            for (int o = 32; o; o >>= 1) f += __shfl_xor(f, o);
            float Iv = Iold[node];
            float h = sHC[ni * 64 + lane] + f * wmLl + Iv * wsLl;
            h = fmaxf(h, 0.f);
            float pb = h * wbl;
            float pg = h * wgl;
#pragma unroll
            for (int o = 32; o; o >>= 1) {
                pb += __shfl_xor(pb, o);
                pg += __shfl_xor(pg, o);
            }
            if (lane == 0) {
                float beta  = 1.f / (1.f + expf(-(pb + bbs)));
                float gamma = 1.f / (1.f + expf(-(pg + bgs)));
                float fc = fminf(fmaxf(f, 0.f), 1000.f);
                float Sv = sS[ni];
                float inf_ = beta * Sv * fc;
                float rec  = gamma * Iv;
                float Sn = fminf(fmaxf(Sv - inf_ * DT_F, 0.f), 1.f);
                float In = fminf(fmaxf(Iv + (inf_ - rec) * DT_F, 0.f), 1.f);
                sS[ni] = Sn;
                Inew[node] = In;
                Iseq[node] = In;
                if (last) { beta_out[node] = beta; gamma_out[node] = gamma; }
            }
        }
        // grid barrier: publish I_new (agent scope), arrive, spin (bounded).
        __threadfence();
        __syncthreads();
        if (tid == 0) {
            __hip_atomic_fetch_add(ctr, 1, __ATOMIC_RELEASE, __HIP_MEMORY_SCOPE_AGENT);
            int target = PK_WGS * (t + 1);
            long cap = 0;
            while (__hip_atomic_load(ctr, __ATOMIC_ACQUIRE, __HIP_MEMORY_SCOPE_AGENT) < target) {
                __builtin_amdgcn_s_sleep(8);
                if (++cap > (1L << 20)) break;   // fail loud, never hang
            }
        }
        __syncthreads();
    }
}

// ---------------------------------------------------------------------------
// Fallback per-step kernel (used only if nper > PK_NCAP).
__global__ void step_fused(const int* __restrict__ rowptr,
                           const int* __restrict__ cols,
                           const float* __restrict__ vals,
                           const float* __restrict__ HC,
                           const float* __restrict__ wmL,
                           const float* __restrict__ wsL,
                           const float* __restrict__ wb, const float* __restrict__ bb,
                           const float* __restrict__ wg, const float* __restrict__ bg,
                           const float* __restrict__ I_old, float* __restrict__ I_new,
                           float* __restrict__ S,
                           float* __restrict__ Iseq_t,
                           float* __restrict__ beta_out, float* __restrict__ gamma_out,
                           int n, int last) {
    int wave = (blockIdx.x * blockDim.x + threadIdx.x) >> 6;
    int lane = threadIdx.x & 63;
    if (wave >= n) return;
    int r0 = rowptr[wave], r1 = rowptr[wave + 1];
    float f = 0.f;
    for (int e = r0 + lane; e < r1; e += 64)
        f = fmaf(vals[e], I_old[cols[e]], f);
#pragma unroll
    for (int o = 32; o; o >>= 1) f += __shfl_xor(f, o);
    float Iv = I_old[wave];
    float h = HC[(size_t)wave * 64 + lane] + f * wmL[lane] + Iv * wsL[lane];
    h = fmaxf(h, 0.f);
    float pb = h * wb[lane];
    float pg = h * wg[lane];
#pragma unroll
    for (int o = 32; o; o >>= 1) {
        pb += __shfl_xor(pb, o);
        pg += __shfl_xor(pg, o);
    }
    if (lane == 0) {
        float beta  = 1.f / (1.f + expf(-(pb + bb[0])));
        float gamma = 1.f / (1.f + expf(-(pg + bg[0])));
        float fc = fminf(fmaxf(f, 0.f), 1000.f);
        float Sv = S[wave];
        float inf_ = beta * Sv * fc;
        float rec  = gamma * Iv;
        float Sn = fminf(fmaxf(Sv - inf_ * DT_F, 0.f), 1.f);
        float In = fminf(fmaxf(Iv + (inf_ - rec) * DT_F, 0.f), 1.f);
        S[wave] = Sn;
        I_new[wave] = In;
        Iseq_t[wave] = In;
        if (last) { beta_out[wave] = beta; gamma_out[wave] = gamma; }
    }
}

// ---------------------------------------------------------------------------
extern "C" void kernel_launch(void* const* d_in, const int* in_sizes, int n_in,
                              void* d_out, int out_size, void* d_ws, size_t ws_size,
                              hipStream_t stream) {
    const float* S0  = (const float*)d_in[0];
    const float* I0  = (const float*)d_in[1];
    const float* nf  = (const float*)d_in[4];
    const void*  ei  = d_in[5];
    const float* ew  = (const float*)d_in[6];
    const float* Wm  = (const float*)d_in[7];
    const float* Wsf = (const float*)d_in[8];
    const float* bh  = (const float*)d_in[9];
    const float* wb  = (const float*)d_in[10];
    const float* bb  = (const float*)d_in[11];
    const float* wg  = (const float*)d_in[12];
    const float* bg  = (const float*)d_in[13];

    const int n = in_sizes[0];
    const int T = in_sizes[3];
    const int E = in_sizes[6];
    const int nb = (n + SCAN_B - 1) / SCAN_B;

    char* ws = (char*)d_ws;
    size_t off = 0;
    auto alloc = [&](size_t bytes) {
        size_t p = off;
        off = (off + bytes + 255) & ~(size_t)255;
        return p;
    };
    float* HC     = (float*)(ws + alloc((size_t)n * 64 * 4));
    float* PM     = (float*)(ws + alloc((size_t)n * 64 * 4));
    float* S      = (float*)(ws + alloc((size_t)n * 4));
    float* Ib0    = (float*)(ws + alloc((size_t)n * 4));
    float* Ib1    = (float*)(ws + alloc((size_t)n * 4));
    int*   cnt    = (int*)(ws + alloc((size_t)n * 4));
    int*   part   = (int*)(ws + alloc((size_t)n * 4));
    int*   bsum   = (int*)(ws + alloc((size_t)SCAN_B * 4));
    int*   rowptr = (int*)(ws + alloc((size_t)(n + 1) * 4));
    int*   cursor = (int*)(ws + alloc((size_t)(n + 1) * 4));
    int*   cols   = (int*)(ws + alloc((size_t)E * 4));
    float* vals   = (float*)(ws + alloc((size_t)E * 4));
    int*   flag   = (int*)(ws + alloc(256));
    int*   ctr    = (int*)(ws + alloc(256));
    if (off > ws_size) return;  // workspace too small: fail loudly (poisoned out)

    float* out       = (float*)d_out;
    float* beta_out  = out + (size_t)T * n;
    float* gamma_out = out + (size_t)T * n + n;

    hipMemsetAsync(cnt, 0, (size_t)n * 4, stream);
    hipMemsetAsync(ctr, 0, 4, stream);

    // CSR build (sorted by dst).
    detect_i64<<<1, 256, 0, stream>>>((const long long*)ei, E, n, flag);
    k_count<<<(E + 255) / 256, 256, 0, stream>>>(ei, flag, E, cnt);
    k_scan1<<<nb, SCAN_B, 0, stream>>>(cnt, part, bsum, n);
    k_scan2<<<1, SCAN_B, 0, stream>>>(bsum, nb);
    k_scan3<<<nb, SCAN_B, 0, stream>>>(part, bsum, rowptr, n, E);
    hipMemcpyAsync(cursor, rowptr, (size_t)n * 4, hipMemcpyDeviceToDevice, stream);
    k_fill<<<(E + 255) / 256, 256, 0, stream>>>(ei, ew, flag, E, cursor, cols, vals);

    // Loop-invariant precompute.
    int pwaves = (n + 3) / 4;
    proj_kernel<<<(pwaves * 64 + 255) / 256, 256, 0, stream>>>(nf, Wm, Wsf, bh, PM, HC, n);
    edge_wide_csr<<<(n * 64 + 255) / 256, 256, 0, stream>>>(rowptr, cols, vals, PM, HC, n);

    const float* wmL = Wm  + 64 * 64;
    const float* wsL = Wsf + 64 * 64;
    int nper = (n + PK_WGS - 1) / PK_WGS;
    if (nper <= PK_NCAP) {
        // All T steps in one persistent dispatch (HC resident in LDS).
        persist_steps<<<PK_WGS, PK_THREADS, 0, stream>>>(
            rowptr, cols, vals, HC, wmL, wsL, wb, bb, wg, bg,
            S0, I0, Ib0, Ib1, out, beta_out, gamma_out, n, T, nper, ctr);
    } else {
        // Fallback: proven per-step path.
        hipMemcpyAsync(S,   S0, (size_t)n * 4, hipMemcpyDeviceToDevice, stream);
        hipMemcpyAsync(Ib0, I0, (size_t)n * 4, hipMemcpyDeviceToDevice, stream);
        for (int t = 0; t < T; ++t) {
            const float* Iold = (t & 1) ? Ib1 : Ib0;
            float*       Inew = (t & 1) ? Ib0 : Ib1;
            step_fused<<<(n * 64 + 255) / 256, 256, 0, stream>>>(
                rowptr, cols, vals, HC, wmL, wsL, wb, bb, wg, bg,
                Iold, Inew, S, out + (size_t)t * n, beta_out, gamma_out,
                n, t == T - 1 ? 1 : 0);
        }
    }
}

// Round 7
// 764.946 us; speedup vs baseline: 4.8299x; 4.8299x over previous
//
#include <hip/hip_runtime.h>
#include <cstdint>
#include <cstddef>

#define DT_F 0.5f

// ---------------------------------------------------------------------------
// edge_index dtype detection (reference says int64; harness doc says int).
__global__ void detect_i64(const long long* __restrict__ ei, int E, int n,
                           int* __restrict__ flag) {
    __shared__ int ok;
    if (threadIdx.x == 0) ok = 1;
    __syncthreads();
    int m = E < 2048 ? E : 2048;
    for (int i = threadIdx.x; i < m; i += blockDim.x) {
        long long v = ei[i];
        if (v < 0 || v >= (long long)n) ok = 0;  // benign race, all write 0
    }
    __syncthreads();
    if (threadIdx.x == 0) flag[0] = ok;
}

__device__ __forceinline__ int ld_idx(const void* ei, size_t pos, int w64) {
    return w64 ? (int)((const long long*)ei)[pos] : ((const int*)ei)[pos];
}

// ---------------------------------------------------------------------------
// CSR build: in-degree histogram -> exclusive scan -> atomic-cursor fill.
__global__ void k_count(const void* __restrict__ ei, const int* __restrict__ flag,
                        int E, int* __restrict__ cnt) {
    int e = blockIdx.x * blockDim.x + threadIdx.x;
    if (e >= E) return;
    int d = ld_idx(ei, (size_t)E + e, flag[0]);
    atomicAdd(&cnt[d], 1);
}

#define SCAN_B 1024
__global__ void k_scan1(const int* __restrict__ cnt, int* __restrict__ part,
                        int* __restrict__ bsum, int n) {
    __shared__ int sh[SCAN_B];
    int t = threadIdx.x;
    int g = blockIdx.x * SCAN_B + t;
    int v = g < n ? cnt[g] : 0;
    sh[t] = v;
    __syncthreads();
    for (int o = 1; o < SCAN_B; o <<= 1) {
        int x = t >= o ? sh[t - o] : 0;
        __syncthreads();
        sh[t] += x;
        __syncthreads();
    }
    if (g < n) part[g] = sh[t] - v;              // exclusive
    if (t == SCAN_B - 1) bsum[blockIdx.x] = sh[t];
}

__global__ void k_scan2(int* __restrict__ bsum, int nb) {  // nb <= 1024
    __shared__ int sh[SCAN_B];
    int t = threadIdx.x;
    int v = t < nb ? bsum[t] : 0;
    sh[t] = v;
    __syncthreads();
    for (int o = 1; o < SCAN_B; o <<= 1) {
        int x = t >= o ? sh[t - o] : 0;
        __syncthreads();
        sh[t] += x;
        __syncthreads();
    }
    if (t < nb) bsum[t] = sh[t] - v;             // exclusive
}

__global__ void k_scan3(const int* __restrict__ part, const int* __restrict__ bsum,
                        int* __restrict__ rowptr, int n, int E) {
    int g = blockIdx.x * SCAN_B + threadIdx.x;
    if (g < n) rowptr[g] = part[g] + bsum[blockIdx.x];
    if (g == 0) rowptr[n] = E;
}

__global__ void k_fill(const void* __restrict__ ei, const float* __restrict__ ew,
                       const int* __restrict__ flag, int E,
                       int* __restrict__ cursor,
                       int* __restrict__ cols, float* __restrict__ vals) {
    int e = blockIdx.x * blockDim.x + threadIdx.x;
    if (e >= E) return;
    int w64 = flag[0];
    int s = ld_idx(ei, e, w64);
    int d = ld_idx(ei, (size_t)E + e, w64);
    int p = atomicAdd(&cursor[d], 1);
    cols[p] = s;
    vals[p] = ew[e];
}

// ---------------------------------------------------------------------------
// Precompute: PM = nf @ W_msg[:64];  HC = nf @ W_self[:64] + b_h.
// 4 nodes per wave -> 8 independent FMA chains (validated correct in R6 run).
__global__ void proj_kernel(const float* __restrict__ nf,
                            const float* __restrict__ Wm,   // (65,64) row-major
                            const float* __restrict__ Wsf,  // (65,64)
                            const float* __restrict__ bh,
                            float* __restrict__ PM, float* __restrict__ HC,
                            int n) {
    __shared__ float sWm[64 * 64];
    __shared__ float sWs[64 * 64];
    for (int i = threadIdx.x; i < 64 * 64; i += blockDim.x) {
        sWm[i] = Wm[i];
        sWs[i] = Wsf[i];
    }
    __syncthreads();
    int wave = (blockIdx.x * blockDim.x + threadIdx.x) >> 6;
    int lane = threadIdx.x & 63;
    int n0 = wave * 4;
    if (n0 >= n) return;
    float a0 = nf[(size_t)n0 * 64 + lane];
    float a1 = (n0 + 1 < n) ? nf[(size_t)(n0 + 1) * 64 + lane] : 0.f;
    float a2 = (n0 + 2 < n) ? nf[(size_t)(n0 + 2) * 64 + lane] : 0.f;
    float a3 = (n0 + 3 < n) ? nf[(size_t)(n0 + 3) * 64 + lane] : 0.f;
    float am0 = 0.f, am1 = 0.f, am2 = 0.f, am3 = 0.f;
    float as0 = 0.f, as1 = 0.f, as2 = 0.f, as3 = 0.f;
#pragma unroll 16
    for (int k = 0; k < 64; ++k) {
        float wmv = sWm[k * 64 + lane];
        float wsv = sWs[k * 64 + lane];
        float v0 = __shfl(a0, k), v1 = __shfl(a1, k);
        float v2 = __shfl(a2, k), v3 = __shfl(a3, k);
        am0 = fmaf(v0, wmv, am0); as0 = fmaf(v0, wsv, as0);
        am1 = fmaf(v1, wmv, am1); as1 = fmaf(v1, wsv, as1);
        am2 = fmaf(v2, wmv, am2); as2 = fmaf(v2, wsv, as2);
        am3 = fmaf(v3, wmv, am3); as3 = fmaf(v3, wsv, as3);
    }
    float bhl = bh[lane];
    PM[(size_t)n0 * 64 + lane] = am0;
    HC[(size_t)n0 * 64 + lane] = as0 + bhl;
    if (n0 + 1 < n) { PM[(size_t)(n0+1)*64 + lane] = am1; HC[(size_t)(n0+1)*64 + lane] = as1 + bhl; }
    if (n0 + 2 < n) { PM[(size_t)(n0+2)*64 + lane] = am2; HC[(size_t)(n0+2)*64 + lane] = as2 + bhl; }
    if (n0 + 3 < n) { PM[(size_t)(n0+3)*64 + lane] = am3; HC[(size_t)(n0+3)*64 + lane] = as3 + bhl; }
}

// Hoisted constant aggregation, CSR form (no atomics):
// HC[d] += sum_{e in in-edges(d)} ew_e * PM[src_e]
__global__ void edge_wide_csr(const int* __restrict__ rowptr,
                              const int* __restrict__ cols,
                              const float* __restrict__ vals,
                              const float* __restrict__ PM,
                              float* __restrict__ HC, int n) {
    int wave = (blockIdx.x * blockDim.x + threadIdx.x) >> 6;
    int lane = threadIdx.x & 63;
    if (wave >= n) return;
    int r0 = rowptr[wave], r1 = rowptr[wave + 1];
    float acc = 0.f;
    for (int e = r0; e < r1; ++e) {
        int s = cols[e];            // wave-uniform broadcast load
        float w = vals[e];
        acc = fmaf(w, PM[(size_t)s * 64 + lane], acc);  // coalesced 256B row
    }
    size_t o = (size_t)wave * 64 + lane;
    HC[o] += acc;
}

// ---------------------------------------------------------------------------
// Fused per-step kernel, 4 nodes per wave / 16 lanes per node.
// Edge loop stride 16 (mean degree ~16 -> all lanes busy, ~1 iteration);
// h in float4 per lane (HC row = 16 float4, coalesced); 4-level reductions.
// I_old is read from out row t-1 (written by the previous step).
__global__ void step_fused4(const int* __restrict__ rowptr,
                            const int* __restrict__ cols,
                            const float* __restrict__ vals,
                            const float4* __restrict__ HC4,
                            const float4* __restrict__ wmL4,  // W_msg row 64
                            const float4* __restrict__ wsL4,  // W_self row 64
                            const float4* __restrict__ wb4, const float* __restrict__ bb,
                            const float4* __restrict__ wg4, const float* __restrict__ bg,
                            const float* __restrict__ I_old,
                            float* __restrict__ S,
                            float* __restrict__ Iseq_t,      // = I_new
                            float* __restrict__ beta_out, float* __restrict__ gamma_out,
                            int n, int last) {
    int wid  = (blockIdx.x * blockDim.x + threadIdx.x) >> 6;
    int lane = threadIdx.x & 63;
    int l16  = lane & 15;
    int node = wid * 4 + (lane >> 4);
    if (node >= n) return;
    int r0 = rowptr[node], r1 = rowptr[node + 1];
    float f = 0.f;
    for (int e = r0 + l16; e < r1; e += 16)
        f = fmaf(vals[e], I_old[cols[e]], f);
    f += __shfl_xor(f, 1); f += __shfl_xor(f, 2);
    f += __shfl_xor(f, 4); f += __shfl_xor(f, 8);   // force, all 16 lanes
    float Iv = I_old[node];
    float4 hc = HC4[(size_t)node * 16 + l16];
    float4 wm = wmL4[l16], wsv = wsL4[l16];
    float4 h;
    h.x = fmaxf(fmaf(f, wm.x, fmaf(Iv, wsv.x, hc.x)), 0.f);
    h.y = fmaxf(fmaf(f, wm.y, fmaf(Iv, wsv.y, hc.y)), 0.f);
    h.z = fmaxf(fmaf(f, wm.z, fmaf(Iv, wsv.z, hc.z)), 0.f);
    h.w = fmaxf(fmaf(f, wm.w, fmaf(Iv, wsv.w, hc.w)), 0.f);
    float4 wbv = wb4[l16], wgv = wg4[l16];
    float pb = fmaf(h.x, wbv.x, fmaf(h.y, wbv.y, fmaf(h.z, wbv.z, h.w * wbv.w)));
    float pg = fmaf(h.x, wgv.x, fmaf(h.y, wgv.y, fmaf(h.z, wgv.z, h.w * wgv.w)));
    pb += __shfl_xor(pb, 1); pg += __shfl_xor(pg, 1);
    pb += __shfl_xor(pb, 2); pg += __shfl_xor(pg, 2);
    pb += __shfl_xor(pb, 4); pg += __shfl_xor(pg, 4);
    pb += __shfl_xor(pb, 8); pg += __shfl_xor(pg, 8);
    if (l16 == 0) {
        float beta  = 1.f / (1.f + expf(-(pb + bb[0])));
        float gamma = 1.f / (1.f + expf(-(pg + bg[0])));
        float fc = fminf(fmaxf(f, 0.f), 1000.f);
        float Sv = S[node];
        float inf_ = beta * Sv * fc;
        float rec  = gamma * Iv;
        float Sn = fminf(fmaxf(Sv - inf_ * DT_F, 0.f), 1.f);
        float In = fminf(fmaxf(Iv + (inf_ - rec) * DT_F, 0.f), 1.f);
        S[node] = Sn;
        Iseq_t[node] = In;                 // doubles as I_new for step t+1
        if (last) { beta_out[node] = beta; gamma_out[node] = gamma; }
    }
}

// ---------------------------------------------------------------------------
extern "C" void kernel_launch(void* const* d_in, const int* in_sizes, int n_in,
                              void* d_out, int out_size, void* d_ws, size_t ws_size,
                              hipStream_t stream) {
    const float* S0  = (const float*)d_in[0];
    const float* I0  = (const float*)d_in[1];
    const float* nf  = (const float*)d_in[4];
    const void*  ei  = d_in[5];
    const float* ew  = (const float*)d_in[6];
    const float* Wm  = (const float*)d_in[7];
    const float* Wsf = (const float*)d_in[8];
    const float* bh  = (const float*)d_in[9];
    const float* wb  = (const float*)d_in[10];
    const float* bb  = (const float*)d_in[11];
    const float* wg  = (const float*)d_in[12];
    const float* bg  = (const float*)d_in[13];

    const int n = in_sizes[0];
    const int T = in_sizes[3];
    const int E = in_sizes[6];
    const int nb = (n + SCAN_B - 1) / SCAN_B;

    char* ws = (char*)d_ws;
    size_t off = 0;
    auto alloc = [&](size_t bytes) {
        size_t p = off;
        off = (off + bytes + 255) & ~(size_t)255;
        return p;
    };
    float* HC     = (float*)(ws + alloc((size_t)n * 64 * 4));
    float* PM     = (float*)(ws + alloc((size_t)n * 64 * 4));
    float* S      = (float*)(ws + alloc((size_t)n * 4));
    int*   cnt    = (int*)(ws + alloc((size_t)n * 4));
    int*   part   = (int*)(ws + alloc((size_t)n * 4));
    int*   bsum   = (int*)(ws + alloc((size_t)SCAN_B * 4));
    int*   rowptr = (int*)(ws + alloc((size_t)(n + 1) * 4));
    int*   cursor = (int*)(ws + alloc((size_t)(n + 1) * 4));
    int*   cols   = (int*)(ws + alloc((size_t)E * 4));
    float* vals   = (float*)(ws + alloc((size_t)E * 4));
    int*   flag   = (int*)(ws + alloc(256));
    if (off > ws_size) return;  // workspace too small: fail loudly (poisoned out)

    float* out       = (float*)d_out;
    float* beta_out  = out + (size_t)T * n;
    float* gamma_out = out + (size_t)T * n + n;

    hipMemcpyAsync(S, S0, (size_t)n * 4, hipMemcpyDeviceToDevice, stream);
    hipMemsetAsync(cnt, 0, (size_t)n * 4, stream);

    // CSR build (sorted by dst).
    detect_i64<<<1, 256, 0, stream>>>((const long long*)ei, E, n, flag);
    k_count<<<(E + 255) / 256, 256, 0, stream>>>(ei, flag, E, cnt);
    k_scan1<<<nb, SCAN_B, 0, stream>>>(cnt, part, bsum, n);
    k_scan2<<<1, SCAN_B, 0, stream>>>(bsum, nb);
    k_scan3<<<nb, SCAN_B, 0, stream>>>(part, bsum, rowptr, n, E);
    hipMemcpyAsync(cursor, rowptr, (size_t)n * 4, hipMemcpyDeviceToDevice, stream);
    k_fill<<<(E + 255) / 256, 256, 0, stream>>>(ei, ew, flag, E, cursor, cols, vals);

    // Loop-invariant precompute.
    int pwaves = (n + 3) / 4;
    proj_kernel<<<(pwaves * 64 + 255) / 256, 256, 0, stream>>>(nf, Wm, Wsf, bh, PM, HC, n);
    edge_wide_csr<<<(n * 64 + 255) / 256, 256, 0, stream>>>(rowptr, cols, vals, PM, HC, n);

    // 20-step scan: one fused kernel/step; I state lives in the out rows.
    const float4* HC4  = (const float4*)HC;
    const float4* wmL4 = (const float4*)(Wm  + 64 * 64);
    const float4* wsL4 = (const float4*)(Wsf + 64 * 64);
    const float4* wb4  = (const float4*)wb;
    const float4* wg4  = (const float4*)wg;
    int swaves = (n + 3) / 4;
    int sblocks = (swaves * 64 + 255) / 256;
    for (int t = 0; t < T; ++t) {
        const float* Iold = (t == 0) ? I0 : out + (size_t)(t - 1) * n;
        step_fused4<<<sblocks, 256, 0, stream>>>(
            rowptr, cols, vals, HC4, wmL4, wsL4, wb4, bb, wg4, bg,
            Iold, S, out + (size_t)t * n, beta_out, gamma_out,
            n, t == T - 1 ? 1 : 0);
    }
}

// Round 8
// 697.233 us; speedup vs baseline: 5.2989x; 1.0971x over previous
//
#include <hip/hip_runtime.h>
#include <cstdint>
#include <cstddef>

#define DT_F 0.5f

// ---------------------------------------------------------------------------
// edge_index dtype detection (reference says int64; harness doc says int).
__global__ void detect_i64(const long long* __restrict__ ei, int E, int n,
                           int* __restrict__ flag) {
    __shared__ int ok;
    if (threadIdx.x == 0) ok = 1;
    __syncthreads();
    int m = E < 2048 ? E : 2048;
    for (int i = threadIdx.x; i < m; i += blockDim.x) {
        long long v = ei[i];
        if (v < 0 || v >= (long long)n) ok = 0;  // benign race, all write 0
    }
    __syncthreads();
    if (threadIdx.x == 0) flag[0] = ok;
}

__device__ __forceinline__ int ld_idx(const void* ei, size_t pos, int w64) {
    return w64 ? (int)((const long long*)ei)[pos] : ((const int*)ei)[pos];
}

// ---------------------------------------------------------------------------
// CSR build: histogram -> exclusive scan over PADDED counts -> cursor fill.
// Rows are padded to a multiple of 4; pad slots stay {col=0, val=0.0f}
// (memset), contributing exactly 0 to every aggregation.
__global__ void k_count(const void* __restrict__ ei, const int* __restrict__ flag,
                        int E, int* __restrict__ cnt) {
    int e = blockIdx.x * blockDim.x + threadIdx.x;
    if (e >= E) return;
    int d = ld_idx(ei, (size_t)E + e, flag[0]);
    atomicAdd(&cnt[d], 1);
}

#define SCAN_B 1024
__global__ void k_scan1(const int* __restrict__ cnt, int* __restrict__ part,
                        int* __restrict__ bsum, int n) {
    __shared__ int sh[SCAN_B];
    int t = threadIdx.x;
    int g = blockIdx.x * SCAN_B + t;
    int v = g < n ? ((cnt[g] + 3) & ~3) : 0;     // padded count
    sh[t] = v;
    __syncthreads();
    for (int o = 1; o < SCAN_B; o <<= 1) {
        int x = t >= o ? sh[t - o] : 0;
        __syncthreads();
        sh[t] += x;
        __syncthreads();
    }
    if (g < n) part[g] = sh[t] - v;              // exclusive
    if (t == SCAN_B - 1) bsum[blockIdx.x] = sh[t];
}

__global__ void k_scan2(int* __restrict__ bsum, int nb) {  // nb <= 1024
    __shared__ int sh[SCAN_B];
    int t = threadIdx.x;
    int v = t < nb ? bsum[t] : 0;
    sh[t] = v;
    __syncthreads();
    for (int o = 1; o < SCAN_B; o <<= 1) {
        int x = t >= o ? sh[t - o] : 0;
        __syncthreads();
        sh[t] += x;
        __syncthreads();
    }
    if (t < nb) bsum[t] = sh[t] - v;             // exclusive
}

__global__ void k_scan3(const int* __restrict__ part, const int* __restrict__ bsum,
                        const int* __restrict__ cnt,
                        int* __restrict__ rowptr, int n) {
    int g = blockIdx.x * SCAN_B + threadIdx.x;
    if (g < n) {
        int r = part[g] + bsum[blockIdx.x];
        rowptr[g] = r;
        if (g == n - 1) rowptr[n] = r + ((cnt[g] + 3) & ~3);  // padded total
    }
}

__global__ void k_fill(const void* __restrict__ ei, const float* __restrict__ ew,
                       const int* __restrict__ flag, int E,
                       int* __restrict__ cursor,
                       int2* __restrict__ ev) {
    int e = blockIdx.x * blockDim.x + threadIdx.x;
    if (e >= E) return;
    int w64 = flag[0];
    int s = ld_idx(ei, e, w64);
    int d = ld_idx(ei, (size_t)E + e, w64);
    int p = atomicAdd(&cursor[d], 1);
    ev[p] = make_int2(s, __float_as_int(ew[e]));   // packed (col, weight)
}

// ---------------------------------------------------------------------------
// Precompute: PM = nf @ W_msg[:64];  HC = nf @ W_self[:64] + b_h.
// 4 nodes per wave -> 8 independent FMA chains (validated in R6/R7 runs).
__global__ void proj_kernel(const float* __restrict__ nf,
                            const float* __restrict__ Wm,   // (65,64) row-major
                            const float* __restrict__ Wsf,  // (65,64)
                            const float* __restrict__ bh,
                            float* __restrict__ PM, float* __restrict__ HC,
                            int n) {
    __shared__ float sWm[64 * 64];
    __shared__ float sWs[64 * 64];
    for (int i = threadIdx.x; i < 64 * 64; i += blockDim.x) {
        sWm[i] = Wm[i];
        sWs[i] = Wsf[i];
    }
    __syncthreads();
    int wave = (blockIdx.x * blockDim.x + threadIdx.x) >> 6;
    int lane = threadIdx.x & 63;
    int n0 = wave * 4;
    if (n0 >= n) return;
    float a0 = nf[(size_t)n0 * 64 + lane];
    float a1 = (n0 + 1 < n) ? nf[(size_t)(n0 + 1) * 64 + lane] : 0.f;
    float a2 = (n0 + 2 < n) ? nf[(size_t)(n0 + 2) * 64 + lane] : 0.f;
    float a3 = (n0 + 3 < n) ? nf[(size_t)(n0 + 3) * 64 + lane] : 0.f;
    float am0 = 0.f, am1 = 0.f, am2 = 0.f, am3 = 0.f;
    float as0 = 0.f, as1 = 0.f, as2 = 0.f, as3 = 0.f;
#pragma unroll 16
    for (int k = 0; k < 64; ++k) {
        float wmv = sWm[k * 64 + lane];
        float wsv = sWs[k * 64 + lane];
        float v0 = __shfl(a0, k), v1 = __shfl(a1, k);
        float v2 = __shfl(a2, k), v3 = __shfl(a3, k);
        am0 = fmaf(v0, wmv, am0); as0 = fmaf(v0, wsv, as0);
        am1 = fmaf(v1, wmv, am1); as1 = fmaf(v1, wsv, as1);
        am2 = fmaf(v2, wmv, am2); as2 = fmaf(v2, wsv, as2);
        am3 = fmaf(v3, wmv, am3); as3 = fmaf(v3, wsv, as3);
    }
    float bhl = bh[lane];
    PM[(size_t)n0 * 64 + lane] = am0;
    HC[(size_t)n0 * 64 + lane] = as0 + bhl;
    if (n0 + 1 < n) { PM[(size_t)(n0+1)*64 + lane] = am1; HC[(size_t)(n0+1)*64 + lane] = as1 + bhl; }
    if (n0 + 2 < n) { PM[(size_t)(n0+2)*64 + lane] = am2; HC[(size_t)(n0+2)*64 + lane] = as2 + bhl; }
    if (n0 + 3 < n) { PM[(size_t)(n0+3)*64 + lane] = am3; HC[(size_t)(n0+3)*64 + lane] = as3 + bhl; }
}

// Hoisted constant aggregation (no atomics), 4-edge unroll with 4 independent
// PM-row loads in flight (rows padded to %4): HC[d] += sum ew_e * PM[src_e].
__global__ void edge_wide_csr(const int* __restrict__ rowptr,
                              const int4* __restrict__ ev4,  // 2 edges per int4
                              const float* __restrict__ PM,
                              float* __restrict__ HC, int n) {
    int wave = (blockIdx.x * blockDim.x + threadIdx.x) >> 6;
    int lane = threadIdx.x & 63;
    if (wave >= n) return;
    int r0 = rowptr[wave], r1 = rowptr[wave + 1];   // both multiples of 4
    float acc0 = 0.f, acc1 = 0.f, acc2 = 0.f, acc3 = 0.f;
    for (int e = r0; e < r1; e += 4) {
        int4 A = ev4[(e >> 1)];        // edges e, e+1
        int4 B = ev4[(e >> 1) + 1];    // edges e+2, e+3
        const float* p0 = PM + (size_t)A.x * 64 + lane;
        const float* p1 = PM + (size_t)A.z * 64 + lane;
        const float* p2 = PM + (size_t)B.x * 64 + lane;
        const float* p3 = PM + (size_t)B.z * 64 + lane;
        float v0 = *p0, v1 = *p1, v2 = *p2, v3 = *p3;   // 4 loads in flight
        acc0 = fmaf(__int_as_float(A.y), v0, acc0);
        acc1 = fmaf(__int_as_float(A.w), v1, acc1);
        acc2 = fmaf(__int_as_float(B.y), v2, acc2);
        acc3 = fmaf(__int_as_float(B.w), v3, acc3);
    }
    size_t o = (size_t)wave * 64 + lane;
    HC[o] += (acc0 + acc1) + (acc2 + acc3);
}

// ---------------------------------------------------------------------------
// Fused per-step kernel, 4 nodes per wave / 16 lanes per node.
// Packed ev: one 8B coalesced load per edge. I_old = out row t-1.
__global__ void step_fused4(const int* __restrict__ rowptr,
                            const int2* __restrict__ ev,
                            const float4* __restrict__ HC4,
                            const float4* __restrict__ wmL4,  // W_msg row 64
                            const float4* __restrict__ wsL4,  // W_self row 64
                            const float4* __restrict__ wb4, const float* __restrict__ bb,
                            const float4* __restrict__ wg4, const float* __restrict__ bg,
                            const float* __restrict__ I_old,
                            float* __restrict__ S,
                            float* __restrict__ Iseq_t,      // = I_new
                            float* __restrict__ beta_out, float* __restrict__ gamma_out,
                            int n, int last) {
    int wid  = (blockIdx.x * blockDim.x + threadIdx.x) >> 6;
    int lane = threadIdx.x & 63;
    int l16  = lane & 15;
    int node = wid * 4 + (lane >> 4);
    if (node >= n) return;
    int r0 = rowptr[node], r1 = rowptr[node + 1];
    float f = 0.f;
    for (int e = r0 + l16; e < r1; e += 16) {
        int2 p = ev[e];
        f = fmaf(__int_as_float(p.y), I_old[p.x], f);
    }
    f += __shfl_xor(f, 1); f += __shfl_xor(f, 2);
    f += __shfl_xor(f, 4); f += __shfl_xor(f, 8);   // force, all 16 lanes
    float Iv = I_old[node];
    float4 hc = HC4[(size_t)node * 16 + l16];
    float4 wm = wmL4[l16], wsv = wsL4[l16];
    float4 h;
    h.x = fmaxf(fmaf(f, wm.x, fmaf(Iv, wsv.x, hc.x)), 0.f);
    h.y = fmaxf(fmaf(f, wm.y, fmaf(Iv, wsv.y, hc.y)), 0.f);
    h.z = fmaxf(fmaf(f, wm.z, fmaf(Iv, wsv.z, hc.z)), 0.f);
    h.w = fmaxf(fmaf(f, wm.w, fmaf(Iv, wsv.w, hc.w)), 0.f);
    float4 wbv = wb4[l16], wgv = wg4[l16];
    float pb = fmaf(h.x, wbv.x, fmaf(h.y, wbv.y, fmaf(h.z, wbv.z, h.w * wbv.w)));
    float pg = fmaf(h.x, wgv.x, fmaf(h.y, wgv.y, fmaf(h.z, wgv.z, h.w * wgv.w)));
    pb += __shfl_xor(pb, 1); pg += __shfl_xor(pg, 1);
    pb += __shfl_xor(pb, 2); pg += __shfl_xor(pg, 2);
    pb += __shfl_xor(pb, 4); pg += __shfl_xor(pg, 4);
    pb += __shfl_xor(pb, 8); pg += __shfl_xor(pg, 8);
    if (l16 == 0) {
        float beta  = 1.f / (1.f + expf(-(pb + bb[0])));
        float gamma = 1.f / (1.f + expf(-(pg + bg[0])));
        float fc = fminf(fmaxf(f, 0.f), 1000.f);
        float Sv = S[node];
        float inf_ = beta * Sv * fc;
        float rec  = gamma * Iv;
        float Sn = fminf(fmaxf(Sv - inf_ * DT_F, 0.f), 1.f);
        float In = fminf(fmaxf(Iv + (inf_ - rec) * DT_F, 0.f), 1.f);
        S[node] = Sn;
        Iseq_t[node] = In;                 // doubles as I_new for step t+1
        if (last) { beta_out[node] = beta; gamma_out[node] = gamma; }
    }
}

// ---------------------------------------------------------------------------
extern "C" void kernel_launch(void* const* d_in, const int* in_sizes, int n_in,
                              void* d_out, int out_size, void* d_ws, size_t ws_size,
                              hipStream_t stream) {
    const float* S0  = (const float*)d_in[0];
    const float* I0  = (const float*)d_in[1];
    const float* nf  = (const float*)d_in[4];
    const void*  ei  = d_in[5];
    const float* ew  = (const float*)d_in[6];
    const float* Wm  = (const float*)d_in[7];
    const float* Wsf = (const float*)d_in[8];
    const float* bh  = (const float*)d_in[9];
    const float* wb  = (const float*)d_in[10];
    const float* bb  = (const float*)d_in[11];
    const float* wg  = (const float*)d_in[12];
    const float* bg  = (const float*)d_in[13];

    const int n = in_sizes[0];
    const int T = in_sizes[3];
    const int E = in_sizes[6];
    const int nb = (n + SCAN_B - 1) / SCAN_B;
    const size_t Epad = (size_t)E + 4 * (size_t)n;  // upper bound on padded edges

    char* ws = (char*)d_ws;
    size_t off = 0;
    auto alloc = [&](size_t bytes) {
        size_t p = off;
        off = (off + bytes + 255) & ~(size_t)255;
        return p;
    };
    float* HC     = (float*)(ws + alloc((size_t)n * 64 * 4));
    float* PM     = (float*)(ws + alloc((size_t)n * 64 * 4));
    float* S      = (float*)(ws + alloc((size_t)n * 4));
    int*   cnt    = (int*)(ws + alloc((size_t)n * 4));
    int*   part   = (int*)(ws + alloc((size_t)n * 4));
    int*   bsum   = (int*)(ws + alloc((size_t)SCAN_B * 4));
    int*   rowptr = (int*)(ws + alloc((size_t)(n + 1) * 4));
    int*   cursor = (int*)(ws + alloc((size_t)(n + 1) * 4));
    int2*  ev     = (int2*)(ws + alloc(Epad * 8));
    int*   flag   = (int*)(ws + alloc(256));
    if (off > ws_size) return;  // workspace too small: fail loudly (poisoned out)

    float* out       = (float*)d_out;
    float* beta_out  = out + (size_t)T * n;
    float* gamma_out = out + (size_t)T * n + n;

    hipMemcpyAsync(S, S0, (size_t)n * 4, hipMemcpyDeviceToDevice, stream);
    hipMemsetAsync(cnt, 0, (size_t)n * 4, stream);
    hipMemsetAsync(ev, 0, Epad * 8, stream);   // pad slots = {col 0, val 0.0f}

    // CSR build (sorted by dst, rows padded to %4).
    detect_i64<<<1, 256, 0, stream>>>((const long long*)ei, E, n, flag);
    k_count<<<(E + 255) / 256, 256, 0, stream>>>(ei, flag, E, cnt);
    k_scan1<<<nb, SCAN_B, 0, stream>>>(cnt, part, bsum, n);
    k_scan2<<<1, SCAN_B, 0, stream>>>(bsum, nb);
    k_scan3<<<nb, SCAN_B, 0, stream>>>(part, bsum, cnt, rowptr, n);
    hipMemcpyAsync(cursor, rowptr, (size_t)n * 4, hipMemcpyDeviceToDevice, stream);
    k_fill<<<(E + 255) / 256, 256, 0, stream>>>(ei, ew, flag, E, cursor, ev);

    // Loop-invariant precompute.
    int pwaves = (n + 3) / 4;
    proj_kernel<<<(pwaves * 64 + 255) / 256, 256, 0, stream>>>(nf, Wm, Wsf, bh, PM, HC, n);
    edge_wide_csr<<<(n * 64 + 255) / 256, 256, 0, stream>>>(rowptr, (const int4*)ev, PM, HC, n);

    // 20-step scan: one fused kernel/step; I state lives in the out rows.
    const float4* HC4  = (const float4*)HC;
    const float4* wmL4 = (const float4*)(Wm  + 64 * 64);
    const float4* wsL4 = (const float4*)(Wsf + 64 * 64);
    const float4* wb4  = (const float4*)wb;
    const float4* wg4  = (const float4*)wg;
    int swaves = (n + 3) / 4;
    int sblocks = (swaves * 64 + 255) / 256;
    for (int t = 0; t < T; ++t) {
        const float* Iold = (t == 0) ? I0 : out + (size_t)(t - 1) * n;
        step_fused4<<<sblocks, 256, 0, stream>>>(
            rowptr, ev, HC4, wmL4, wsL4, wb4, bb, wg4, bg,
            Iold, S, out + (size_t)t * n, beta_out, gamma_out,
            n, t == T - 1 ? 1 : 0);
    }
}

// Round 10
// 658.046 us; speedup vs baseline: 5.6145x; 1.0595x over previous
//
#include <hip/hip_runtime.h>
#include <cstdint>
#include <cstddef>

#define DT_F 0.5f
#define KF_CHUNKS 768   // edge chunks; grid = KF_CHUNKS * 8 slice-blocks

// ---------------------------------------------------------------------------
// edge_index dtype detection (reference says int64; harness doc says int).
__global__ void detect_i64(const long long* __restrict__ ei, int E, int n,
                           int* __restrict__ flag) {
    __shared__ int ok;
    if (threadIdx.x == 0) ok = 1;
    __syncthreads();
    int m = E < 2048 ? E : 2048;
    for (int i = threadIdx.x; i < m; i += blockDim.x) {
        long long v = ei[i];
        if (v < 0 || v >= (long long)n) ok = 0;  // benign race, all write 0
    }
    __syncthreads();
    if (threadIdx.x == 0) flag[0] = ok;
}

__device__ __forceinline__ int ld_idx(const void* ei, size_t pos, int w64) {
    return w64 ? (int)((const long long*)ei)[pos] : ((const int*)ei)[pos];
}

// ---------------------------------------------------------------------------
// CSR build, XCD-sliced: dst-space is cut into 8 contiguous slices; block b
// processes edge-chunk (b>>3) and emits only edges with dst in slice (b&7).
// blockIdx%8 -> XCD (round-robin dispatch) => each slice's counter/ev region
// is written by ONE XCD only: scattered writes coalesce in its private L2
// instead of one line-eviction per write (R8: 99MB writeback for 13MB data).
__global__ void k_count_sliced(const void* __restrict__ ei,
                               const int* __restrict__ flag,
                               int E, int n, int* __restrict__ cnt) {
    int slice = blockIdx.x & 7;
    int chunk = blockIdx.x >> 3;
    int per = (E + KF_CHUNKS - 1) / KF_CHUNKS;
    int e0 = chunk * per;
    int e1 = e0 + per; if (e1 > E) e1 = E;
    int w64 = flag[0];
    int lo = (int)(((long long)n * slice) >> 3);
    int hi = (int)(((long long)n * (slice + 1)) >> 3);
    for (int e = e0 + (int)threadIdx.x; e < e1; e += blockDim.x) {
        int d = ld_idx(ei, (size_t)E + e, w64);
        if (d >= lo && d < hi) atomicAdd(&cnt[d], 1);
    }
}

#define SCAN_B 1024
__global__ void k_scan1(const int* __restrict__ cnt, int* __restrict__ part,
                        int* __restrict__ bsum, int n) {
    __shared__ int sh[SCAN_B];
    int t = threadIdx.x;
    int g = blockIdx.x * SCAN_B + t;
    int v = g < n ? ((cnt[g] + 3) & ~3) : 0;     // padded count
    sh[t] = v;
    __syncthreads();
    for (int o = 1; o < SCAN_B; o <<= 1) {
        int x = t >= o ? sh[t - o] : 0;
        __syncthreads();
        sh[t] += x;
        __syncthreads();
    }
    if (g < n) part[g] = sh[t] - v;              // exclusive
    if (t == SCAN_B - 1) bsum[blockIdx.x] = sh[t];
}

__global__ void k_scan2(int* __restrict__ bsum, int nb) {  // nb <= 1024
    __shared__ int sh[SCAN_B];
    int t = threadIdx.x;
    int v = t < nb ? bsum[t] : 0;
    sh[t] = v;
    __syncthreads();
    for (int o = 1; o < SCAN_B; o <<= 1) {
        int x = t >= o ? sh[t - o] : 0;
        __syncthreads();
        sh[t] += x;
        __syncthreads();
    }
    if (t < nb) bsum[t] = sh[t] - v;             // exclusive
}

__global__ void k_scan3(const int* __restrict__ part, const int* __restrict__ bsum,
                        const int* __restrict__ cnt,
                        int* __restrict__ rowptr, int n) {
    int g = blockIdx.x * SCAN_B + threadIdx.x;
    if (g < n) {
        int r = part[g] + bsum[blockIdx.x];
        rowptr[g] = r;
        if (g == n - 1) rowptr[n] = r + ((cnt[g] + 3) & ~3);  // padded total
    }
}

__global__ void k_fill_sliced(const void* __restrict__ ei,
                              const float* __restrict__ ew,
                              const int* __restrict__ flag, int E, int n,
                              int* __restrict__ cursor,
                              int2* __restrict__ ev) {
    int slice = blockIdx.x & 7;
    int chunk = blockIdx.x >> 3;
    int per = (E + KF_CHUNKS - 1) / KF_CHUNKS;
    int e0 = chunk * per;
    int e1 = e0 + per; if (e1 > E) e1 = E;
    int w64 = flag[0];
    int lo = (int)(((long long)n * slice) >> 3);
    int hi = (int)(((long long)n * (slice + 1)) >> 3);
    for (int e = e0 + (int)threadIdx.x; e < e1; e += blockDim.x) {
        int d = ld_idx(ei, (size_t)E + e, w64);
        if (d < lo || d >= hi) continue;
        int s = ld_idx(ei, e, w64);
        int p = atomicAdd(&cursor[d], 1);
        ev[p] = make_int2(s, __float_as_int(ew[e]));   // packed (col, weight)
    }
}

// ---------------------------------------------------------------------------
// Precompute: PM = nf @ W_msg[:64];  HC = nf @ W_self[:64] + b_h.
// 4 nodes per wave -> 8 independent FMA chains (validated in R6-R8 runs).
__global__ void proj_kernel(const float* __restrict__ nf,
                            const float* __restrict__ Wm,   // (65,64) row-major
                            const float* __restrict__ Wsf,  // (65,64)
                            const float* __restrict__ bh,
                            float* __restrict__ PM, float* __restrict__ HC,
                            int n) {
    __shared__ float sWm[64 * 64];
    __shared__ float sWs[64 * 64];
    for (int i = threadIdx.x; i < 64 * 64; i += blockDim.x) {
        sWm[i] = Wm[i];
        sWs[i] = Wsf[i];
    }
    __syncthreads();
    int wave = (blockIdx.x * blockDim.x + threadIdx.x) >> 6;
    int lane = threadIdx.x & 63;
    int n0 = wave * 4;
    if (n0 >= n) return;
    float a0 = nf[(size_t)n0 * 64 + lane];
    float a1 = (n0 + 1 < n) ? nf[(size_t)(n0 + 1) * 64 + lane] : 0.f;
    float a2 = (n0 + 2 < n) ? nf[(size_t)(n0 + 2) * 64 + lane] : 0.f;
    float a3 = (n0 + 3 < n) ? nf[(size_t)(n0 + 3) * 64 + lane] : 0.f;
    float am0 = 0.f, am1 = 0.f, am2 = 0.f, am3 = 0.f;
    float as0 = 0.f, as1 = 0.f, as2 = 0.f, as3 = 0.f;
#pragma unroll 16
    for (int k = 0; k < 64; ++k) {
        float wmv = sWm[k * 64 + lane];
        float wsv = sWs[k * 64 + lane];
        float v0 = __shfl(a0, k), v1 = __shfl(a1, k);
        float v2 = __shfl(a2, k), v3 = __shfl(a3, k);
        am0 = fmaf(v0, wmv, am0); as0 = fmaf(v0, wsv, as0);
        am1 = fmaf(v1, wmv, am1); as1 = fmaf(v1, wsv, as1);
        am2 = fmaf(v2, wmv, am2); as2 = fmaf(v2, wsv, as2);
        am3 = fmaf(v3, wmv, am3); as3 = fmaf(v3, wsv, as3);
    }
    float bhl = bh[lane];
    PM[(size_t)n0 * 64 + lane] = am0;
    HC[(size_t)n0 * 64 + lane] = as0 + bhl;
    if (n0 + 1 < n) { PM[(size_t)(n0+1)*64 + lane] = am1; HC[(size_t)(n0+1)*64 + lane] = as1 + bhl; }
    if (n0 + 2 < n) { PM[(size_t)(n0+2)*64 + lane] = am2; HC[(size_t)(n0+2)*64 + lane] = as2 + bhl; }
    if (n0 + 3 < n) { PM[(size_t)(n0+3)*64 + lane] = am3; HC[(size_t)(n0+3)*64 + lane] = as3 + bhl; }
}

// Hoisted constant aggregation (no atomics), 4-edge unroll with 4 independent
// PM-row loads in flight (rows padded to %4): HC[d] += sum ew_e * PM[src_e].
__global__ void edge_wide_csr(const int* __restrict__ rowptr,
                              const int4* __restrict__ ev4,  // 2 edges per int4
                              const float* __restrict__ PM,
                              float* __restrict__ HC, int n) {
    int wave = (blockIdx.x * blockDim.x + threadIdx.x) >> 6;
    int lane = threadIdx.x & 63;
    if (wave >= n) return;
    int r0 = rowptr[wave], r1 = rowptr[wave + 1];   // both multiples of 4
    float acc0 = 0.f, acc1 = 0.f, acc2 = 0.f, acc3 = 0.f;
    for (int e = r0; e < r1; e += 4) {
        int4 A = ev4[(e >> 1)];        // edges e, e+1
        int4 B = ev4[(e >> 1) + 1];    // edges e+2, e+3
        const float* p0 = PM + (size_t)A.x * 64 + lane;
        const float* p1 = PM + (size_t)A.z * 64 + lane;
        const float* p2 = PM + (size_t)B.x * 64 + lane;
        const float* p3 = PM + (size_t)B.z * 64 + lane;
        float v0 = *p0, v1 = *p1, v2 = *p2, v3 = *p3;   // 4 loads in flight
        acc0 = fmaf(__int_as_float(A.y), v0, acc0);
        acc1 = fmaf(__int_as_float(A.w), v1, acc1);
        acc2 = fmaf(__int_as_float(B.y), v2, acc2);
        acc3 = fmaf(__int_as_float(B.w), v3, acc3);
    }
    size_t o = (size_t)wave * 64 + lane;
    HC[o] += (acc0 + acc1) + (acc2 + acc3);
}

// ---------------------------------------------------------------------------
// Fused per-step kernel, 4 nodes per wave / 16 lanes per node.
// Packed ev: one 8B coalesced load per edge. I_old = out row t-1.
__global__ void step_fused4(const int* __restrict__ rowptr,
                            const int2* __restrict__ ev,
                            const float4* __restrict__ HC4,
                            const float4* __restrict__ wmL4,  // W_msg row 64
                            const float4* __restrict__ wsL4,  // W_self row 64
                            const float4* __restrict__ wb4, const float* __restrict__ bb,
                            const float4* __restrict__ wg4, const float* __restrict__ bg,
                            const float* __restrict__ I_old,
                            float* __restrict__ S,
                            float* __restrict__ Iseq_t,      // = I_new
                            float* __restrict__ beta_out, float* __restrict__ gamma_out,
                            int n, int last) {
    int wid  = (blockIdx.x * blockDim.x + threadIdx.x) >> 6;
    int lane = threadIdx.x & 63;
    int l16  = lane & 15;
    int node = wid * 4 + (lane >> 4);
    if (node >= n) return;
    int r0 = rowptr[node], r1 = rowptr[node + 1];
    float f = 0.f;
    for (int e = r0 + l16; e < r1; e += 16) {
        int2 p = ev[e];
        f = fmaf(__int_as_float(p.y), I_old[p.x], f);
    }
    f += __shfl_xor(f, 1); f += __shfl_xor(f, 2);
    f += __shfl_xor(f, 4); f += __shfl_xor(f, 8);   // force, all 16 lanes
    float Iv = I_old[node];
    float4 hc = HC4[(size_t)node * 16 + l16];
    float4 wm = wmL4[l16], wsv = wsL4[l16];
    float4 h;
    h.x = fmaxf(fmaf(f, wm.x, fmaf(Iv, wsv.x, hc.x)), 0.f);
    h.y = fmaxf(fmaf(f, wm.y, fmaf(Iv, wsv.y, hc.y)), 0.f);
    h.z = fmaxf(fmaf(f, wm.z, fmaf(Iv, wsv.z, hc.z)), 0.f);
    h.w = fmaxf(fmaf(f, wm.w, fmaf(Iv, wsv.w, hc.w)), 0.f);
    float4 wbv = wb4[l16], wgv = wg4[l16];
    float pb = fmaf(h.x, wbv.x, fmaf(h.y, wbv.y, fmaf(h.z, wbv.z, h.w * wbv.w)));
    float pg = fmaf(h.x, wgv.x, fmaf(h.y, wgv.y, fmaf(h.z, wgv.z, h.w * wgv.w)));
    pb += __shfl_xor(pb, 1); pg += __shfl_xor(pg, 1);
    pb += __shfl_xor(pb, 2); pg += __shfl_xor(pg, 2);
    pb += __shfl_xor(pb, 4); pg += __shfl_xor(pg, 4);
    pb += __shfl_xor(pb, 8); pg += __shfl_xor(pg, 8);
    if (l16 == 0) {
        float beta  = 1.f / (1.f + expf(-(pb + bb[0])));
        float gamma = 1.f / (1.f + expf(-(pg + bg[0])));
        float fc = fminf(fmaxf(f, 0.f), 1000.f);
        float Sv = S[node];
        float inf_ = beta * Sv * fc;
        float rec  = gamma * Iv;
        float Sn = fminf(fmaxf(Sv - inf_ * DT_F, 0.f), 1.f);
        float In = fminf(fmaxf(Iv + (inf_ - rec) * DT_F, 0.f), 1.f);
        S[node] = Sn;
        Iseq_t[node] = In;                 // doubles as I_new for step t+1
        if (last) { beta_out[node] = beta; gamma_out[node] = gamma; }
    }
}

// ---------------------------------------------------------------------------
extern "C" void kernel_launch(void* const* d_in, const int* in_sizes, int n_in,
                              void* d_out, int out_size, void* d_ws, size_t ws_size,
                              hipStream_t stream) {
    const float* S0  = (const float*)d_in[0];
    const float* I0  = (const float*)d_in[1];
    const float* nf  = (const float*)d_in[4];
    const void*  ei  = d_in[5];
    const float* ew  = (const float*)d_in[6];
    const float* Wm  = (const float*)d_in[7];
    const float* Wsf = (const float*)d_in[8];
    const float* bh  = (const float*)d_in[9];
    const float* wb  = (const float*)d_in[10];
    const float* bb  = (const float*)d_in[11];
    const float* wg  = (const float*)d_in[12];
    const float* bg  = (const float*)d_in[13];

    const int n = in_sizes[0];
    const int T = in_sizes[3];
    const int E = in_sizes[6];
    const int nb = (n + SCAN_B - 1) / SCAN_B;
    const size_t Epad = (size_t)E + 4 * (size_t)n;  // upper bound on padded edges

    char* ws = (char*)d_ws;
    size_t off = 0;
    auto alloc = [&](size_t bytes) {
        size_t p = off;
        off = (off + bytes + 255) & ~(size_t)255;
        return p;
    };
    float* HC     = (float*)(ws + alloc((size_t)n * 64 * 4));
    float* PM     = (float*)(ws + alloc((size_t)n * 64 * 4));
    float* S      = (float*)(ws + alloc((size_t)n * 4));
    int*   cnt    = (int*)(ws + alloc((size_t)n * 4));
    int*   part   = (int*)(ws + alloc((size_t)n * 4));
    int*   bsum   = (int*)(ws + alloc((size_t)SCAN_B * 4));
    int*   rowptr = (int*)(ws + alloc((size_t)(n + 1) * 4));
    int*   cursor = (int*)(ws + alloc((size_t)(n + 1) * 4));
    int2*  ev     = (int2*)(ws + alloc(Epad * 8));
    int*   flag   = (int*)(ws + alloc(256));
    if (off > ws_size) return;  // workspace too small: fail loudly (poisoned out)

    float* out       = (float*)d_out;
    float* beta_out  = out + (size_t)T * n;
    float* gamma_out = out + (size_t)T * n + n;

    hipMemcpyAsync(S, S0, (size_t)n * 4, hipMemcpyDeviceToDevice, stream);
    hipMemsetAsync(cnt, 0, (size_t)n * 4, stream);
    hipMemsetAsync(ev, 0, Epad * 8, stream);   // pad slots = {col 0, val 0.0f}

    // CSR build (sorted by dst, rows padded to %4), XCD-sliced scatters.
    detect_i64<<<1, 256, 0, stream>>>((const long long*)ei, E, n, flag);
    k_count_sliced<<<KF_CHUNKS * 8, 256, 0, stream>>>(ei, flag, E, n, cnt);
    k_scan1<<<nb, SCAN_B, 0, stream>>>(cnt, part, bsum, n);
    k_scan2<<<1, SCAN_B, 0, stream>>>(bsum, nb);
    k_scan3<<<nb, SCAN_B, 0, stream>>>(part, bsum, cnt, rowptr, n);
    hipMemcpyAsync(cursor, rowptr, (size_t)n * 4, hipMemcpyDeviceToDevice, stream);
    k_fill_sliced<<<KF_CHUNKS * 8, 256, 0, stream>>>(ei, ew, flag, E, n, cursor, ev);

    // Loop-invariant precompute.
    int pwaves = (n + 3) / 4;
    proj_kernel<<<(pwaves * 64 + 255) / 256, 256, 0, stream>>>(nf, Wm, Wsf, bh, PM, HC, n);
    edge_wide_csr<<<(n * 64 + 255) / 256, 256, 0, stream>>>(rowptr, (const int4*)ev, PM, HC, n);

    // 20-step scan: one fused kernel/step; I state lives in the out rows.
    const float4* HC4  = (const float4*)HC;
    const float4* wmL4 = (const float4*)(Wm  + 64 * 64);
    const float4* wsL4 = (const float4*)(Wsf + 64 * 64);
    const float4* wb4  = (const float4*)wb;
    const float4* wg4  = (const float4*)wg;
    int swaves = (n + 3) / 4;
    int sblocks = (swaves * 64 + 255) / 256;
    for (int t = 0; t < T; ++t) {
        const float* Iold = (t == 0) ? I0 : out + (size_t)(t - 1) * n;
        step_fused4<<<sblocks, 256, 0, stream>>>(
            rowptr, ev, HC4, wmL4, wsL4, wb4, bb, wg4, bg,
            Iold, S, out + (size_t)t * n, beta_out, gamma_out,
            n, t == T - 1 ? 1 : 0);
    }
}

// Round 11
// 616.938 us; speedup vs baseline: 5.9886x; 1.0666x over previous
//
#include <hip/hip_runtime.h>
#include <cstdint>
#include <cstddef>

#define DT_F 0.5f
#define KF_CHUNKS 768   // edge chunks; grid = KF_CHUNKS * 8 slice-blocks

// ---------------------------------------------------------------------------
// edge_index dtype detection (reference says int64; harness doc says int).
__global__ void detect_i64(const long long* __restrict__ ei, int E, int n,
                           int* __restrict__ flag) {
    __shared__ int ok;
    if (threadIdx.x == 0) ok = 1;
    __syncthreads();
    int m = E < 2048 ? E : 2048;
    for (int i = threadIdx.x; i < m; i += blockDim.x) {
        long long v = ei[i];
        if (v < 0 || v >= (long long)n) ok = 0;  // benign race, all write 0
    }
    __syncthreads();
    if (threadIdx.x == 0) flag[0] = ok;
}

__device__ __forceinline__ int ld_idx(const void* ei, size_t pos, int w64) {
    return w64 ? (int)((const long long*)ei)[pos] : ((const int*)ei)[pos];
}

// ---------------------------------------------------------------------------
// CSR build, XCD-sliced (validated R10: killed the 99MB writeback storm).
__global__ void k_count_sliced(const void* __restrict__ ei,
                               const int* __restrict__ flag,
                               int E, int n, int* __restrict__ cnt) {
    int slice = blockIdx.x & 7;
    int chunk = blockIdx.x >> 3;
    int per = (E + KF_CHUNKS - 1) / KF_CHUNKS;
    int e0 = chunk * per;
    int e1 = e0 + per; if (e1 > E) e1 = E;
    int w64 = flag[0];
    int lo = (int)(((long long)n * slice) >> 3);
    int hi = (int)(((long long)n * (slice + 1)) >> 3);
    for (int e = e0 + (int)threadIdx.x; e < e1; e += blockDim.x) {
        int d = ld_idx(ei, (size_t)E + e, w64);
        if (d >= lo && d < hi) atomicAdd(&cnt[d], 1);
    }
}

#define SCAN_B 1024
__global__ void k_scan1(const int* __restrict__ cnt, int* __restrict__ part,
                        int* __restrict__ bsum, int n) {
    __shared__ int sh[SCAN_B];
    int t = threadIdx.x;
    int g = blockIdx.x * SCAN_B + t;
    int v = g < n ? ((cnt[g] + 3) & ~3) : 0;     // padded count
    sh[t] = v;
    __syncthreads();
    for (int o = 1; o < SCAN_B; o <<= 1) {
        int x = t >= o ? sh[t - o] : 0;
        __syncthreads();
        sh[t] += x;
        __syncthreads();
    }
    if (g < n) part[g] = sh[t] - v;              // exclusive
    if (t == SCAN_B - 1) bsum[blockIdx.x] = sh[t];
}

__global__ void k_scan2(int* __restrict__ bsum, int nb) {  // nb <= 1024
    __shared__ int sh[SCAN_B];
    int t = threadIdx.x;
    int v = t < nb ? bsum[t] : 0;
    sh[t] = v;
    __syncthreads();
    for (int o = 1; o < SCAN_B; o <<= 1) {
        int x = t >= o ? sh[t - o] : 0;
        __syncthreads();
        sh[t] += x;
        __syncthreads();
    }
    if (t < nb) bsum[t] = sh[t] - v;             // exclusive
}

__global__ void k_scan3(const int* __restrict__ part, const int* __restrict__ bsum,
                        const int* __restrict__ cnt,
                        int* __restrict__ rowptr, int n) {
    int g = blockIdx.x * SCAN_B + threadIdx.x;
    if (g < n) {
        int r = part[g] + bsum[blockIdx.x];
        rowptr[g] = r;
        if (g == n - 1) rowptr[n] = r + ((cnt[g] + 3) & ~3);  // padded total
    }
}

__global__ void k_fill_sliced(const void* __restrict__ ei,
                              const float* __restrict__ ew,
                              const int* __restrict__ flag, int E, int n,
                              int* __restrict__ cursor,
                              int2* __restrict__ ev) {
    int slice = blockIdx.x & 7;
    int chunk = blockIdx.x >> 3;
    int per = (E + KF_CHUNKS - 1) / KF_CHUNKS;
    int e0 = chunk * per;
    int e1 = e0 + per; if (e1 > E) e1 = E;
    int w64 = flag[0];
    int lo = (int)(((long long)n * slice) >> 3);
    int hi = (int)(((long long)n * (slice + 1)) >> 3);
    for (int e = e0 + (int)threadIdx.x; e < e1; e += blockDim.x) {
        int d = ld_idx(ei, (size_t)E + e, w64);
        if (d < lo || d >= hi) continue;
        int s = ld_idx(ei, e, w64);
        int p = atomicAdd(&cursor[d], 1);
        ev[p] = make_int2(s, __float_as_int(ew[e]));   // packed (col, weight)
    }
}

// ---------------------------------------------------------------------------
// Tiled, shuffle-free proj: PM = nf @ Wm[:64], HC = nf @ Ws[:64] + b_h.
// Block = 256 thr (4 waves), tile = 64 nodes. W^T in LDS [64][65] (b32 reads,
// 2-way bank alias = free); nf tile [64][68] (272B rows -> aligned float4
// reads at wave-uniform address = broadcast). Wave owns 16 nodes, lane j owns
// feature j; 32 statically-indexed accumulators = 32 independent FMA chains.
__global__ void proj_tiled(const float* __restrict__ nf,
                           const float* __restrict__ Wm,   // (65,64) row-major
                           const float* __restrict__ Wsf,  // (65,64)
                           const float* __restrict__ bh,
                           float* __restrict__ PM, float* __restrict__ HC,
                           int n) {
    __shared__ float sWmT[64 * 65];
    __shared__ float sWsT[64 * 65];
    __shared__ float sNf[64 * 68];
    for (int i = threadIdx.x; i < 64 * 64; i += 256) {
        int k = i >> 6, j = i & 63;
        sWmT[j * 65 + k] = Wm[i];       // coalesced read, 2-way LDS write
        sWsT[j * 65 + k] = Wsf[i];
    }
    int node0 = blockIdx.x * 64;
    for (int i = threadIdx.x; i < 64 * 64; i += 256) {
        int r = i >> 6, c = i & 63;
        if (node0 + r < n) sNf[r * 68 + c] = nf[(size_t)(node0 + r) * 64 + c];
    }
    __syncthreads();
    int w   = threadIdx.x >> 6;        // wave 0..3 -> nodes w*16..w*16+15
    int j   = threadIdx.x & 63;        // output feature
    float accm[16], accs[16];
#pragma unroll
    for (int ni = 0; ni < 16; ++ni) { accm[ni] = 0.f; accs[ni] = 0.f; }
    for (int kq = 0; kq < 16; ++kq) {
        int k = kq * 4;
        float wm0 = sWmT[j * 65 + k],     wm1 = sWmT[j * 65 + k + 1];
        float wm2 = sWmT[j * 65 + k + 2], wm3 = sWmT[j * 65 + k + 3];
        float ws0 = sWsT[j * 65 + k],     ws1 = sWsT[j * 65 + k + 1];
        float ws2 = sWsT[j * 65 + k + 2], ws3 = sWsT[j * 65 + k + 3];
#pragma unroll
        for (int ni = 0; ni < 16; ++ni) {
            float4 a = *(const float4*)&sNf[(w * 16 + ni) * 68 + k];
            accm[ni] = fmaf(a.w, wm3, fmaf(a.z, wm2, fmaf(a.y, wm1, fmaf(a.x, wm0, accm[ni]))));
            accs[ni] = fmaf(a.w, ws3, fmaf(a.z, ws2, fmaf(a.y, ws1, fmaf(a.x, ws0, accs[ni]))));
        }
    }
    float bhl = bh[j];
#pragma unroll
    for (int ni = 0; ni < 16; ++ni) {
        int node = node0 + w * 16 + ni;
        if (node < n) {
            PM[(size_t)node * 64 + j] = accm[ni];
            HC[(size_t)node * 64 + j] = accs[ni] + bhl;
        }
    }
}

// Hoisted constant aggregation (no atomics), 4-edge unroll with 4 independent
// PM-row loads in flight (rows padded to %4): HC[d] += sum ew_e * PM[src_e].
__global__ void edge_wide_csr(const int* __restrict__ rowptr,
                              const int4* __restrict__ ev4,  // 2 edges per int4
                              const float* __restrict__ PM,
                              float* __restrict__ HC, int n) {
    int wave = (blockIdx.x * blockDim.x + threadIdx.x) >> 6;
    int lane = threadIdx.x & 63;
    if (wave >= n) return;
    int r0 = rowptr[wave], r1 = rowptr[wave + 1];   // both multiples of 4
    float acc0 = 0.f, acc1 = 0.f, acc2 = 0.f, acc3 = 0.f;
    for (int e = r0; e < r1; e += 4) {
        int4 A = ev4[(e >> 1)];        // edges e, e+1
        int4 B = ev4[(e >> 1) + 1];    // edges e+2, e+3
        const float* p0 = PM + (size_t)A.x * 64 + lane;
        const float* p1 = PM + (size_t)A.z * 64 + lane;
        const float* p2 = PM + (size_t)B.x * 64 + lane;
        const float* p3 = PM + (size_t)B.z * 64 + lane;
        float v0 = *p0, v1 = *p1, v2 = *p2, v3 = *p3;   // 4 loads in flight
        acc0 = fmaf(__int_as_float(A.y), v0, acc0);
        acc1 = fmaf(__int_as_float(A.w), v1, acc1);
        acc2 = fmaf(__int_as_float(B.y), v2, acc2);
        acc3 = fmaf(__int_as_float(B.w), v3, acc3);
    }
    size_t o = (size_t)wave * 64 + lane;
    HC[o] += (acc0 + acc1) + (acc2 + acc3);
}

// ---------------------------------------------------------------------------
// Fused per-step kernel, 4 nodes per wave / 16 lanes per node (validated).
__global__ void step_fused4(const int* __restrict__ rowptr,
                            const int2* __restrict__ ev,
                            const float4* __restrict__ HC4,
                            const float4* __restrict__ wmL4,  // W_msg row 64
                            const float4* __restrict__ wsL4,  // W_self row 64
                            const float4* __restrict__ wb4, const float* __restrict__ bb,
                            const float4* __restrict__ wg4, const float* __restrict__ bg,
                            const float* __restrict__ I_old,
                            float* __restrict__ S,
                            float* __restrict__ Iseq_t,      // = I_new
                            float* __restrict__ beta_out, float* __restrict__ gamma_out,
                            int n, int last) {
    int wid  = (blockIdx.x * blockDim.x + threadIdx.x) >> 6;
    int lane = threadIdx.x & 63;
    int l16  = lane & 15;
    int node = wid * 4 + (lane >> 4);
    if (node >= n) return;
    int r0 = rowptr[node], r1 = rowptr[node + 1];
    float f = 0.f;
    for (int e = r0 + l16; e < r1; e += 16) {
        int2 p = ev[e];
        f = fmaf(__int_as_float(p.y), I_old[p.x], f);
    }
    f += __shfl_xor(f, 1); f += __shfl_xor(f, 2);
    f += __shfl_xor(f, 4); f += __shfl_xor(f, 8);   // force, all 16 lanes
    float Iv = I_old[node];
    float4 hc = HC4[(size_t)node * 16 + l16];
    float4 wm = wmL4[l16], wsv = wsL4[l16];
    float4 h;
    h.x = fmaxf(fmaf(f, wm.x, fmaf(Iv, wsv.x, hc.x)), 0.f);
    h.y = fmaxf(fmaf(f, wm.y, fmaf(Iv, wsv.y, hc.y)), 0.f);
    h.z = fmaxf(fmaf(f, wm.z, fmaf(Iv, wsv.z, hc.z)), 0.f);
    h.w = fmaxf(fmaf(f, wm.w, fmaf(Iv, wsv.w, hc.w)), 0.f);
    float4 wbv = wb4[l16], wgv = wg4[l16];
    float pb = fmaf(h.x, wbv.x, fmaf(h.y, wbv.y, fmaf(h.z, wbv.z, h.w * wbv.w)));
    float pg = fmaf(h.x, wgv.x, fmaf(h.y, wgv.y, fmaf(h.z, wgv.z, h.w * wgv.w)));
    pb += __shfl_xor(pb, 1); pg += __shfl_xor(pg, 1);
    pb += __shfl_xor(pb, 2); pg += __shfl_xor(pg, 2);
    pb += __shfl_xor(pb, 4); pg += __shfl_xor(pg, 4);
    pb += __shfl_xor(pb, 8); pg += __shfl_xor(pg, 8);
    if (l16 == 0) {
        float beta  = 1.f / (1.f + expf(-(pb + bb[0])));
        float gamma = 1.f / (1.f + expf(-(pg + bg[0])));
        float fc = fminf(fmaxf(f, 0.f), 1000.f);
        float Sv = S[node];
        float inf_ = beta * Sv * fc;
        float rec  = gamma * Iv;
        float Sn = fminf(fmaxf(Sv - inf_ * DT_F, 0.f), 1.f);
        float In = fminf(fmaxf(Iv + (inf_ - rec) * DT_F, 0.f), 1.f);
        S[node] = Sn;
        Iseq_t[node] = In;                 // doubles as I_new for step t+1
        if (last) { beta_out[node] = beta; gamma_out[node] = gamma; }
    }
}

// ---------------------------------------------------------------------------
extern "C" void kernel_launch(void* const* d_in, const int* in_sizes, int n_in,
                              void* d_out, int out_size, void* d_ws, size_t ws_size,
                              hipStream_t stream) {
    const float* S0  = (const float*)d_in[0];
    const float* I0  = (const float*)d_in[1];
    const float* nf  = (const float*)d_in[4];
    const void*  ei  = d_in[5];
    const float* ew  = (const float*)d_in[6];
    const float* Wm  = (const float*)d_in[7];
    const float* Wsf = (const float*)d_in[8];
    const float* bh  = (const float*)d_in[9];
    const float* wb  = (const float*)d_in[10];
    const float* bb  = (const float*)d_in[11];
    const float* wg  = (const float*)d_in[12];
    const float* bg  = (const float*)d_in[13];

    const int n = in_sizes[0];
    const int T = in_sizes[3];
    const int E = in_sizes[6];
    const int nb = (n + SCAN_B - 1) / SCAN_B;
    const size_t Epad = (size_t)E + 4 * (size_t)n;  // upper bound on padded edges

    char* ws = (char*)d_ws;
    size_t off = 0;
    auto alloc = [&](size_t bytes) {
        size_t p = off;
        off = (off + bytes + 255) & ~(size_t)255;
        return p;
    };
    float* HC     = (float*)(ws + alloc((size_t)n * 64 * 4));
    float* PM     = (float*)(ws + alloc((size_t)n * 64 * 4));
    float* S      = (float*)(ws + alloc((size_t)n * 4));
    int*   cnt    = (int*)(ws + alloc((size_t)n * 4));
    int*   part   = (int*)(ws + alloc((size_t)n * 4));
    int*   bsum   = (int*)(ws + alloc((size_t)SCAN_B * 4));
    int*   rowptr = (int*)(ws + alloc((size_t)(n + 1) * 4));
    int*   cursor = (int*)(ws + alloc((size_t)(n + 1) * 4));
    int2*  ev     = (int2*)(ws + alloc(Epad * 8));
    int*   flag   = (int*)(ws + alloc(256));
    if (off > ws_size) return;  // workspace too small: fail loudly (poisoned out)

    float* out       = (float*)d_out;
    float* beta_out  = out + (size_t)T * n;
    float* gamma_out = out + (size_t)T * n + n;

    hipMemcpyAsync(S, S0, (size_t)n * 4, hipMemcpyDeviceToDevice, stream);
    hipMemsetAsync(cnt, 0, (size_t)n * 4, stream);
    hipMemsetAsync(ev, 0, Epad * 8, stream);   // pad slots = {col 0, val 0.0f}

    // CSR build (sorted by dst, rows padded to %4), XCD-sliced scatters.
    detect_i64<<<1, 256, 0, stream>>>((const long long*)ei, E, n, flag);
    k_count_sliced<<<KF_CHUNKS * 8, 256, 0, stream>>>(ei, flag, E, n, cnt);
    k_scan1<<<nb, SCAN_B, 0, stream>>>(cnt, part, bsum, n);
    k_scan2<<<1, SCAN_B, 0, stream>>>(bsum, nb);
    k_scan3<<<nb, SCAN_B, 0, stream>>>(part, bsum, cnt, rowptr, n);
    hipMemcpyAsync(cursor, rowptr, (size_t)n * 4, hipMemcpyDeviceToDevice, stream);
    k_fill_sliced<<<KF_CHUNKS * 8, 256, 0, stream>>>(ei, ew, flag, E, n, cursor, ev);

    // Loop-invariant precompute.
    proj_tiled<<<(n + 63) / 64, 256, 0, stream>>>(nf, Wm, Wsf, bh, PM, HC, n);
    edge_wide_csr<<<(n * 64 + 255) / 256, 256, 0, stream>>>(rowptr, (const int4*)ev, PM, HC, n);

    // 20-step scan: one fused kernel/step; I state lives in the out rows.
    const float4* HC4  = (const float4*)HC;
    const float4* wmL4 = (const float4*)(Wm  + 64 * 64);
    const float4* wsL4 = (const float4*)(Wsf + 64 * 64);
    const float4* wb4  = (const float4*)wb;
    const float4* wg4  = (const float4*)wg;
    int swaves = (n + 3) / 4;
    int sblocks = (swaves * 64 + 255) / 256;
    for (int t = 0; t < T; ++t) {
        const float* Iold = (t == 0) ? I0 : out + (size_t)(t - 1) * n;
        step_fused4<<<sblocks, 256, 0, stream>>>(
            rowptr, ev, HC4, wmL4, wsL4, wb4, bb, wg4, bg,
            Iold, S, out + (size_t)t * n, beta_out, gamma_out,
            n, t == T - 1 ? 1 : 0);
    }
}

// Round 12
// 566.776 us; speedup vs baseline: 6.5186x; 1.0885x over previous
//
#include <hip/hip_runtime.h>
#include <hip/hip_fp16.h>
#include <cstdint>
#include <cstddef>

#define DT_F 0.5f
#define KF_CHUNKS 768   // edge chunks; grid = KF_CHUNKS * 8 slice-blocks

// ---------------------------------------------------------------------------
// edge_index dtype detection (reference says int64; harness doc says int).
__global__ void detect_i64(const long long* __restrict__ ei, int E, int n,
                           int* __restrict__ flag) {
    __shared__ int ok;
    if (threadIdx.x == 0) ok = 1;
    __syncthreads();
    int m = E < 2048 ? E : 2048;
    for (int i = threadIdx.x; i < m; i += blockDim.x) {
        long long v = ei[i];
        if (v < 0 || v >= (long long)n) ok = 0;  // benign race, all write 0
    }
    __syncthreads();
    if (threadIdx.x == 0) flag[0] = ok;
}

__device__ __forceinline__ int ld_idx(const void* ei, size_t pos, int w64) {
    return w64 ? (int)((const long long*)ei)[pos] : ((const int*)ei)[pos];
}

// ---------------------------------------------------------------------------
// CSR build, XCD-sliced (validated R10: cut k_fill 122->72 us).
__global__ void k_count_sliced(const void* __restrict__ ei,
                               const int* __restrict__ flag,
                               int E, int n, int* __restrict__ cnt) {
    int slice = blockIdx.x & 7;
    int chunk = blockIdx.x >> 3;
    int per = (E + KF_CHUNKS - 1) / KF_CHUNKS;
    int e0 = chunk * per;
    int e1 = e0 + per; if (e1 > E) e1 = E;
    int w64 = flag[0];
    int lo = (int)(((long long)n * slice) >> 3);
    int hi = (int)(((long long)n * (slice + 1)) >> 3);
    for (int e = e0 + (int)threadIdx.x; e < e1; e += blockDim.x) {
        int d = ld_idx(ei, (size_t)E + e, w64);
        if (d >= lo && d < hi) atomicAdd(&cnt[d], 1);
    }
}

#define SCAN_B 1024
__global__ void k_scan1(const int* __restrict__ cnt, int* __restrict__ part,
                        int* __restrict__ bsum, int n) {
    __shared__ int sh[SCAN_B];
    int t = threadIdx.x;
    int g = blockIdx.x * SCAN_B + t;
    int v = g < n ? ((cnt[g] + 3) & ~3) : 0;     // padded count
    sh[t] = v;
    __syncthreads();
    for (int o = 1; o < SCAN_B; o <<= 1) {
        int x = t >= o ? sh[t - o] : 0;
        __syncthreads();
        sh[t] += x;
        __syncthreads();
    }
    if (g < n) part[g] = sh[t] - v;              // exclusive
    if (t == SCAN_B - 1) bsum[blockIdx.x] = sh[t];
}

__global__ void k_scan2(int* __restrict__ bsum, int nb) {  // nb <= 1024
    __shared__ int sh[SCAN_B];
    int t = threadIdx.x;
    int v = t < nb ? bsum[t] : 0;
    sh[t] = v;
    __syncthreads();
    for (int o = 1; o < SCAN_B; o <<= 1) {
        int x = t >= o ? sh[t - o] : 0;
        __syncthreads();
        sh[t] += x;
        __syncthreads();
    }
    if (t < nb) bsum[t] = sh[t] - v;             // exclusive
}

__global__ void k_scan3(const int* __restrict__ part, const int* __restrict__ bsum,
                        const int* __restrict__ cnt,
                        int* __restrict__ rowptr, int n) {
    int g = blockIdx.x * SCAN_B + threadIdx.x;
    if (g < n) {
        int r = part[g] + bsum[blockIdx.x];
        rowptr[g] = r;
        if (g == n - 1) rowptr[n] = r + ((cnt[g] + 3) & ~3);  // padded total
    }
}

// Packed edge: high (32-colbits) bits = 15-bit fixed-point weight, low = col.
// 4 B/edge halves every downstream edge stream (step loop x20, edge_wide).
__global__ void k_fill_sliced(const void* __restrict__ ei,
                              const float* __restrict__ ew,
                              const int* __restrict__ flag, int E, int n,
                              int* __restrict__ cursor,
                              uint32_t* __restrict__ ev,
                              int colbits, float scale) {
    int slice = blockIdx.x & 7;
    int chunk = blockIdx.x >> 3;
    int per = (E + KF_CHUNKS - 1) / KF_CHUNKS;
    int e0 = chunk * per;
    int e1 = e0 + per; if (e1 > E) e1 = E;
    int w64 = flag[0];
    int lo = (int)(((long long)n * slice) >> 3);
    int hi = (int)(((long long)n * (slice + 1)) >> 3);
    for (int e = e0 + (int)threadIdx.x; e < e1; e += blockDim.x) {
        int d = ld_idx(ei, (size_t)E + e, w64);
        if (d < lo || d >= hi) continue;
        int s = ld_idx(ei, e, w64);
        uint32_t w15 = (uint32_t)(ew[e] * scale + 0.5f);
        int p = atomicAdd(&cursor[d], 1);
        ev[p] = (w15 << colbits) | (uint32_t)s;
    }
}

// ---------------------------------------------------------------------------
// Tiled, shuffle-free proj (validated R11: left top-5): PM = nf@Wm, HC = nf@Ws+bh.
__global__ void proj_tiled(const float* __restrict__ nf,
                           const float* __restrict__ Wm,   // (65,64) row-major
                           const float* __restrict__ Wsf,  // (65,64)
                           const float* __restrict__ bh,
                           float* __restrict__ PM, float* __restrict__ HC,
                           int n) {
    __shared__ float sWmT[64 * 65];
    __shared__ float sWsT[64 * 65];
    __shared__ float sNf[64 * 68];
    for (int i = threadIdx.x; i < 64 * 64; i += 256) {
        int k = i >> 6, j = i & 63;
        sWmT[j * 65 + k] = Wm[i];
        sWsT[j * 65 + k] = Wsf[i];
    }
    int node0 = blockIdx.x * 64;
    for (int i = threadIdx.x; i < 64 * 64; i += 256) {
        int r = i >> 6, c = i & 63;
        if (node0 + r < n) sNf[r * 68 + c] = nf[(size_t)(node0 + r) * 64 + c];
    }
    __syncthreads();
    int w   = threadIdx.x >> 6;
    int j   = threadIdx.x & 63;
    float accm[16], accs[16];
#pragma unroll
    for (int ni = 0; ni < 16; ++ni) { accm[ni] = 0.f; accs[ni] = 0.f; }
    for (int kq = 0; kq < 16; ++kq) {
        int k = kq * 4;
        float wm0 = sWmT[j * 65 + k],     wm1 = sWmT[j * 65 + k + 1];
        float wm2 = sWmT[j * 65 + k + 2], wm3 = sWmT[j * 65 + k + 3];
        float ws0 = sWsT[j * 65 + k],     ws1 = sWsT[j * 65 + k + 1];
        float ws2 = sWsT[j * 65 + k + 2], ws3 = sWsT[j * 65 + k + 3];
#pragma unroll
        for (int ni = 0; ni < 16; ++ni) {
            float4 a = *(const float4*)&sNf[(w * 16 + ni) * 68 + k];
            accm[ni] = fmaf(a.w, wm3, fmaf(a.z, wm2, fmaf(a.y, wm1, fmaf(a.x, wm0, accm[ni]))));
            accs[ni] = fmaf(a.w, ws3, fmaf(a.z, ws2, fmaf(a.y, ws1, fmaf(a.x, ws0, accs[ni]))));
        }
    }
    float bhl = bh[j];
#pragma unroll
    for (int ni = 0; ni < 16; ++ni) {
        int node = node0 + w * 16 + ni;
        if (node < n) {
            PM[(size_t)node * 64 + j] = accm[ni];
            HC[(size_t)node * 64 + j] = accs[ni] + bhl;
        }
    }
}

// Hoisted constant aggregation; uint4 = 4 packed edges per 16B load; emits
// the scan-resident constant as fp16 (halves the 20x-reread HC stream).
__global__ void edge_wide_csr(const int* __restrict__ rowptr,
                              const uint32_t* __restrict__ ev,
                              const float* __restrict__ PM,
                              const float* __restrict__ HCin,
                              __half* __restrict__ HCh, int n,
                              int colbits, float inv_scale) {
    int wave = (blockIdx.x * blockDim.x + threadIdx.x) >> 6;
    int lane = threadIdx.x & 63;
    if (wave >= n) return;
    uint32_t cmask = (1u << colbits) - 1;
    int r0 = rowptr[wave], r1 = rowptr[wave + 1];   // both multiples of 4
    float acc0 = 0.f, acc1 = 0.f, acc2 = 0.f, acc3 = 0.f;
    for (int e = r0; e < r1; e += 4) {
        uint4 q = *(const uint4*)&ev[e];   // 4 edges, 16B aligned
        float v0 = PM[(size_t)(q.x & cmask) * 64 + lane];
        float v1 = PM[(size_t)(q.y & cmask) * 64 + lane];
        float v2 = PM[(size_t)(q.z & cmask) * 64 + lane];
        float v3 = PM[(size_t)(q.w & cmask) * 64 + lane];
        acc0 = fmaf((float)(q.x >> colbits) * inv_scale, v0, acc0);
        acc1 = fmaf((float)(q.y >> colbits) * inv_scale, v1, acc1);
        acc2 = fmaf((float)(q.z >> colbits) * inv_scale, v2, acc2);
        acc3 = fmaf((float)(q.w >> colbits) * inv_scale, v3, acc3);
    }
    size_t o = (size_t)wave * 64 + lane;
    HCh[o] = __float2half(HCin[o] + ((acc0 + acc1) + (acc2 + acc3)));
}

// ---------------------------------------------------------------------------
// Fused per-step kernel, 4 nodes/wave, 16 lanes/node. Packed 4B edges +
// fp16 HC: ~23 MB/step (was 44). I_old = out row t-1.
__global__ void step_fused4(const int* __restrict__ rowptr,
                            const uint32_t* __restrict__ ev,
                            const __half2* __restrict__ HCh2,
                            const float4* __restrict__ wmL4,  // W_msg row 64
                            const float4* __restrict__ wsL4,  // W_self row 64
                            const float4* __restrict__ wb4, const float* __restrict__ bb,
                            const float4* __restrict__ wg4, const float* __restrict__ bg,
                            const float* __restrict__ I_old,
                            float* __restrict__ S,
                            float* __restrict__ Iseq_t,      // = I_new
                            float* __restrict__ beta_out, float* __restrict__ gamma_out,
                            int n, int last, int colbits, float inv_scale) {
    int wid  = (blockIdx.x * blockDim.x + threadIdx.x) >> 6;
    int lane = threadIdx.x & 63;
    int l16  = lane & 15;
    int node = wid * 4 + (lane >> 4);
    if (node >= n) return;
    uint32_t cmask = (1u << colbits) - 1;
    int r0 = rowptr[node], r1 = rowptr[node + 1];
    float f = 0.f;
    for (int e = r0 + l16; e < r1; e += 16) {
        uint32_t p = ev[e];
        f = fmaf((float)(p >> colbits) * inv_scale, I_old[p & cmask], f);
    }
    f += __shfl_xor(f, 1); f += __shfl_xor(f, 2);
    f += __shfl_xor(f, 4); f += __shfl_xor(f, 8);   // force, all 16 lanes
    float Iv = I_old[node];
    __half2 hA = HCh2[(size_t)node * 32 + l16 * 2];
    __half2 hB = HCh2[(size_t)node * 32 + l16 * 2 + 1];
    float2 fA = __half22float2(hA);
    float2 fB = __half22float2(hB);
    float4 wm = wmL4[l16], wsv = wsL4[l16];
    float4 h;
    h.x = fmaxf(fmaf(f, wm.x, fmaf(Iv, wsv.x, fA.x)), 0.f);
    h.y = fmaxf(fmaf(f, wm.y, fmaf(Iv, wsv.y, fA.y)), 0.f);
    h.z = fmaxf(fmaf(f, wm.z, fmaf(Iv, wsv.z, fB.x)), 0.f);
    h.w = fmaxf(fmaf(f, wm.w, fmaf(Iv, wsv.w, fB.y)), 0.f);
    float4 wbv = wb4[l16], wgv = wg4[l16];
    float pb = fmaf(h.x, wbv.x, fmaf(h.y, wbv.y, fmaf(h.z, wbv.z, h.w * wbv.w)));
    float pg = fmaf(h.x, wgv.x, fmaf(h.y, wgv.y, fmaf(h.z, wgv.z, h.w * wgv.w)));
    pb += __shfl_xor(pb, 1); pg += __shfl_xor(pg, 1);
    pb += __shfl_xor(pb, 2); pg += __shfl_xor(pg, 2);
    pb += __shfl_xor(pb, 4); pg += __shfl_xor(pg, 4);
    pb += __shfl_xor(pb, 8); pg += __shfl_xor(pg, 8);
    if (l16 == 0) {
        float beta  = 1.f / (1.f + expf(-(pb + bb[0])));
        float gamma = 1.f / (1.f + expf(-(pg + bg[0])));
        float fc = fminf(fmaxf(f, 0.f), 1000.f);
        float Sv = S[node];
        float inf_ = beta * Sv * fc;
        float rec  = gamma * Iv;
        float Sn = fminf(fmaxf(Sv - inf_ * DT_F, 0.f), 1.f);
        float In = fminf(fmaxf(Iv + (inf_ - rec) * DT_F, 0.f), 1.f);
        S[node] = Sn;
        Iseq_t[node] = In;                 // doubles as I_new for step t+1
        if (last) { beta_out[node] = beta; gamma_out[node] = gamma; }
    }
}

// ---------------------------------------------------------------------------
extern "C" void kernel_launch(void* const* d_in, const int* in_sizes, int n_in,
                              void* d_out, int out_size, void* d_ws, size_t ws_size,
                              hipStream_t stream) {
    const float* S0  = (const float*)d_in[0];
    const float* I0  = (const float*)d_in[1];
    const float* nf  = (const float*)d_in[4];
    const void*  ei  = d_in[5];
    const float* ew  = (const float*)d_in[6];
    const float* Wm  = (const float*)d_in[7];
    const float* Wsf = (const float*)d_in[8];
    const float* bh  = (const float*)d_in[9];
    const float* wb  = (const float*)d_in[10];
    const float* bb  = (const float*)d_in[11];
    const float* wg  = (const float*)d_in[12];
    const float* bg  = (const float*)d_in[13];

    const int n = in_sizes[0];
    const int T = in_sizes[3];
    const int E = in_sizes[6];
    const int nb = (n + SCAN_B - 1) / SCAN_B;
    const size_t Epad = (size_t)E + 4 * (size_t)n;  // upper bound on padded edges

    int colbits = 1;
    while ((1 << colbits) < n) ++colbits;           // n <= 2^colbits (17 @ 100K)
    float scale = (float)((1u << (32 - colbits)) - 1);
    float inv_scale = 1.0f / scale;

    char* ws = (char*)d_ws;
    size_t off = 0;
    auto alloc = [&](size_t bytes) {
        size_t p = off;
        off = (off + bytes + 255) & ~(size_t)255;
        return p;
    };
    float*  HC     = (float*)(ws + alloc((size_t)n * 64 * 4));
    float*  PM     = (float*)(ws + alloc((size_t)n * 64 * 4));
    __half* HCh    = (__half*)(ws + alloc((size_t)n * 64 * 2));
    float*  S      = (float*)(ws + alloc((size_t)n * 4));
    int*    cnt    = (int*)(ws + alloc((size_t)n * 4));
    int*    part   = (int*)(ws + alloc((size_t)n * 4));
    int*    bsum   = (int*)(ws + alloc((size_t)SCAN_B * 4));
    int*    rowptr = (int*)(ws + alloc((size_t)(n + 1) * 4));
    int*    cursor = (int*)(ws + alloc((size_t)(n + 1) * 4));
    uint32_t* ev   = (uint32_t*)(ws + alloc(Epad * 4));
    int*    flag   = (int*)(ws + alloc(256));
    if (off > ws_size) return;  // workspace too small: fail loudly (poisoned out)

    float* out       = (float*)d_out;
    float* beta_out  = out + (size_t)T * n;
    float* gamma_out = out + (size_t)T * n + n;

    hipMemcpyAsync(S, S0, (size_t)n * 4, hipMemcpyDeviceToDevice, stream);
    hipMemsetAsync(cnt, 0, (size_t)n * 4, stream);
    hipMemsetAsync(ev, 0, Epad * 4, stream);   // pad slots = {w 0, col 0}

    // CSR build (sorted by dst, rows padded to %4), XCD-sliced scatters.
    detect_i64<<<1, 256, 0, stream>>>((const long long*)ei, E, n, flag);
    k_count_sliced<<<KF_CHUNKS * 8, 256, 0, stream>>>(ei, flag, E, n, cnt);
    k_scan1<<<nb, SCAN_B, 0, stream>>>(cnt, part, bsum, n);
    k_scan2<<<1, SCAN_B, 0, stream>>>(bsum, nb);
    k_scan3<<<nb, SCAN_B, 0, stream>>>(part, bsum, cnt, rowptr, n);
    hipMemcpyAsync(cursor, rowptr, (size_t)n * 4, hipMemcpyDeviceToDevice, stream);
    k_fill_sliced<<<KF_CHUNKS * 8, 256, 0, stream>>>(ei, ew, flag, E, n, cursor,
                                                     ev, colbits, scale);

    // Loop-invariant precompute.
    proj_tiled<<<(n + 63) / 64, 256, 0, stream>>>(nf, Wm, Wsf, bh, PM, HC, n);
    edge_wide_csr<<<(n * 64 + 255) / 256, 256, 0, stream>>>(
        rowptr, ev, PM, HC, HCh, n, colbits, inv_scale);

    // 20-step scan: one fused kernel/step; I state lives in the out rows.
    const __half2* HCh2 = (const __half2*)HCh;
    const float4* wmL4 = (const float4*)(Wm  + 64 * 64);
    const float4* wsL4 = (const float4*)(Wsf + 64 * 64);
    const float4* wb4  = (const float4*)wb;
    const float4* wg4  = (const float4*)wg;
    int swaves = (n + 3) / 4;
    int sblocks = (swaves * 64 + 255) / 256;
    for (int t = 0; t < T; ++t) {
        const float* Iold = (t == 0) ? I0 : out + (size_t)(t - 1) * n;
        step_fused4<<<sblocks, 256, 0, stream>>>(
            rowptr, ev, HCh2, wmL4, wsL4, wb4, bb, wg4, bg,
            Iold, S, out + (size_t)t * n, beta_out, gamma_out,
            n, t == T - 1 ? 1 : 0, colbits, inv_scale);
    }
}